// Round 3
// baseline (517.206 us; speedup 1.0000x reference)
//
#include <hip/hip_runtime.h>

typedef unsigned short u16;
typedef __attribute__((ext_vector_type(4))) float f32x4;
typedef __attribute__((ext_vector_type(8))) short s16x8;

#define TOK 8192
#define NDIM 768
#define NHEADS 12
#define QK_SCALE 0.125f
#define WHN 192            // window-heads
#define WHSZ 32768         // 512*64 elements per window-head plane

__device__ __forceinline__ u16 f2bf(float f) {
  union { float f; unsigned u; } x; x.f = f;
  unsigned r = x.u + 0x7fffu + ((x.u >> 16) & 1u);
  return (u16)(r >> 16);
}
__device__ __forceinline__ float bf2f(u16 u) {
  union { unsigned u; float f; } x; x.u = ((unsigned)u) << 16;
  return x.f;
}
__device__ __forceinline__ float gelu_f(float v) {
  return 0.5f * v * (1.0f + erff(v * 0.70710678118654752f));
}
__device__ __forceinline__ f32x4 mfma16(s16x8 a, s16x8 b, f32x4 c) {
  return __builtin_amdgcn_mfma_f32_16x16x32_bf16(a, b, c, 0, 0, 0);
}
__device__ __forceinline__ void glds16(const u16* g, u16* l) {
  __builtin_amdgcn_global_load_lds(
      (const __attribute__((address_space(1))) unsigned int*)g,
      (__attribute__((address_space(3))) unsigned int*)l, 16, 0, 0);
}
// window (wi in [0,16), n in [0,512)) -> flat spatial token index
__device__ __forceinline__ int tok_of(int wi, int n) {
  int b = wi >> 3;
  int d = (((wi >> 2) & 1) << 3) | (n >> 6);
  int h = (((wi >> 1) & 1) << 3) | ((n >> 3) & 7);
  int w = ((wi & 1) << 3) | (n & 7);
  return (b << 12) | (d << 8) | (h << 4) | w;
}

// ---------------- weight fp32 -> bf16 ----------------
struct WConv {
  const float* src[8];
  u16* dst[8];
  int n[8];
};
__global__ __launch_bounds__(256) void conv_weights(WConv a) {
  int stride = gridDim.x * blockDim.x;
  int t0 = blockIdx.x * blockDim.x + threadIdx.x;
  for (int s = 0; s < 8; s++) {
    const float4* src = (const float4*)a.src[s];
    u16* dst = a.dst[s];
    int n4 = a.n[s] >> 2;
    for (int i = t0; i < n4; i += stride) {
      float4 v = src[i];
      ushort4 o;
      o.x = f2bf(v.x); o.y = f2bf(v.y); o.z = f2bf(v.z); o.w = f2bf(v.w);
      *(ushort4*)(dst + 4 * (size_t)i) = o;
    }
  }
}

// ---------------- LayerNorm (fp32 in -> bf16 out) ----------------
__global__ __launch_bounds__(256) void ln_bf16(const float* __restrict__ in,
    const float* __restrict__ gamma, const float* __restrict__ beta,
    u16* __restrict__ out) {
  const int row = blockIdx.x;
  const int tid = threadIdx.x;
  const float* xr = in + (size_t)row * NDIM;
  float v0 = xr[tid], v1 = xr[tid + 256], v2 = xr[tid + 512];
  float s = v0 + v1 + v2;
  float q = v0 * v0 + v1 * v1 + v2 * v2;
  for (int o = 32; o; o >>= 1) { s += __shfl_down(s, o); q += __shfl_down(q, o); }
  __shared__ float ss[4], sq[4];
  int wave = tid >> 6, lane = tid & 63;
  if (lane == 0) { ss[wave] = s; sq[wave] = q; }
  __syncthreads();
  s = ss[0] + ss[1] + ss[2] + ss[3];
  q = sq[0] + sq[1] + sq[2] + sq[3];
  float mean = s * (1.0f / 768.0f);
  float var = q * (1.0f / 768.0f) - mean * mean;
  float rstd = rsqrtf(var + 1e-5f);
  u16* orow = out + (size_t)row * NDIM;
  float v[3] = {v0, v1, v2};
  #pragma unroll
  for (int i = 0; i < 3; i++) {
    int c = tid + i * 256;
    orow[c] = f2bf((v[i] - mean) * rstd * gamma[c] + beta[c]);
  }
}

// ---------------- GEMM: C[M,N] = A[M,K](bf16) * W[N,K]^T(bf16) + bias, epilogues ----------------
// EPI 0: bf16 store; 1: f32+bf16 store; 2: gelu->bf16; 3: h=add1+add2+v ->f32;
// EPI 4: out=add1+v ->f32; 5: out=add1+0.5v ->f32; 6: packed QKV store per window-head
template<int BN, int EPI>
__global__ __launch_bounds__(256) void gemm_bf16(
    const u16* __restrict__ A, const u16* __restrict__ W,
    const float* __restrict__ bias, int M, int N, int K,
    u16* __restrict__ obf, float* __restrict__ of,
    const float* __restrict__ add1, const float* __restrict__ add2) {
  constexpr int BM = 128, BK = 32;
  constexpr int WN = BN / 2;
  constexpr int MF = 4, NF = WN / 16;
  constexpr int ACH = BM * BK / (8 * 256);  // 16B chunks per thread for A
  constexpr int BCH = BN * BK / (8 * 256);
  __shared__ __align__(16) u16 As[BM * BK];
  __shared__ __align__(16) u16 Bs[BN * BK];
  const int bm = blockIdx.x, bn = blockIdx.y;
  const int tid = threadIdx.x;
  const int wave = tid >> 6, lane = tid & 63;
  const int wr = wave >> 1, wc = wave & 1;
  const int g = lane >> 4, c15 = lane & 15;
  f32x4 acc[MF][NF] = {};
  const u16* Ab = A + (size_t)(bm * BM) * K;
  const u16* Wb = W + (size_t)(bn * BN) * K;
  for (int k0 = 0; k0 < K; k0 += BK) {
    #pragma unroll
    for (int i = 0; i < ACH; i++) {
      int L = i * 256 + tid;
      glds16(Ab + (size_t)(L >> 2) * K + k0 + (L & 3) * 8, &As[L * 8]);
    }
    #pragma unroll
    for (int i = 0; i < BCH; i++) {
      int L = i * 256 + tid;
      glds16(Wb + (size_t)(L >> 2) * K + k0 + (L & 3) * 8, &Bs[L * 8]);
    }
    __syncthreads();
    s16x8 af[MF], bfr[NF];
    #pragma unroll
    for (int mi = 0; mi < MF; mi++)
      af[mi] = *(const s16x8*)&As[(wr * 64 + mi * 16 + c15) * BK + g * 8];
    #pragma unroll
    for (int ni = 0; ni < NF; ni++)
      bfr[ni] = *(const s16x8*)&Bs[(wc * WN + ni * 16 + c15) * BK + g * 8];
    #pragma unroll
    for (int mi = 0; mi < MF; mi++)
      #pragma unroll
      for (int ni = 0; ni < NF; ni++)
        acc[mi][ni] = mfma16(af[mi], bfr[ni], acc[mi][ni]);
    __syncthreads();
  }
  #pragma unroll
  for (int mi = 0; mi < MF; mi++) {
    #pragma unroll
    for (int ni = 0; ni < NF; ni++) {
      int col = bn * BN + wc * WN + ni * 16 + c15;
      float bv = bias[col];
      #pragma unroll
      for (int j = 0; j < 4; j++) {
        int row = bm * BM + wr * 64 + mi * 16 + g * 4 + j;
        size_t idx = (size_t)row * N + col;
        float v = acc[mi][ni][j] + bv;
        if (EPI == 0) {
          obf[idx] = f2bf(v);
        } else if (EPI == 1) {
          of[idx] = v; obf[idx] = f2bf(v);
        } else if (EPI == 2) {
          obf[idx] = f2bf(gelu_f(v));
        } else if (EPI == 3) {
          of[idx] = add1[idx] + add2[idx] + v;
        } else if (EPI == 4) {
          of[idx] = add1[idx] + v;
        } else if (EPI == 5) {
          of[idx] = add1[idx] + 0.5f * v;
        } else if (EPI == 6) {
          // packed QKV: seg 0/1/2 -> Qp/Kp/Vp [whi][n][64]
          int seg = col >= 1536 ? 2 : (col >= 768 ? 1 : 0);
          int cc_ = col - seg * 768;
          int hh = cc_ >> 6, c = cc_ & 63;
          int t = row;
          int b = t >> 12, d = (t >> 8) & 15, hy = (t >> 4) & 15, wx = t & 15;
          int wi = (b << 3) | ((d >> 3) << 2) | ((hy >> 3) << 1) | (wx >> 3);
          int n = ((d & 7) << 6) | ((hy & 7) << 3) | (wx & 7);
          obf[(size_t)seg * (WHN * WHSZ) +
              ((size_t)(wi * NHEADS + hh) * 512 + n) * 64 + c] = f2bf(v);
        }
      }
    }
  }
}

// ---------------- transpose Vp[whi][n][c] -> Vt[whi][c][n] ----------------
__global__ __launch_bounds__(256) void repack_v(const u16* __restrict__ vp,
                                                u16* __restrict__ vt) {
  int whi = blockIdx.x;
  __shared__ u16 Vs[512 * 64];  // XOR-swizzled: slot(n,c) = n*64 + (c ^ (n&63))
  int tid = threadIdx.x;
  const u16* src = vp + (size_t)whi * WHSZ;
  for (int idx = tid; idx < 512 * 64; idx += 256) {
    int n = idx >> 6, c = idx & 63;
    Vs[(n << 6) | (c ^ (n & 63))] = src[idx];
  }
  __syncthreads();
  size_t base = (size_t)whi * WHSZ;
  #pragma unroll 1
  for (int i = 0; i < 32; i++) {
    int idx4 = tid + i * 256;  // 0..8191
    int c = idx4 >> 7, np = (idx4 & 127) << 2;
    ushort4 o;
    o.x = Vs[((np + 0) << 6) | (c ^ ((np + 0) & 63))];
    o.y = Vs[((np + 1) << 6) | (c ^ ((np + 1) & 63))];
    o.z = Vs[((np + 2) << 6) | (c ^ ((np + 2) & 63))];
    o.w = Vs[((np + 3) << 6) | (c ^ ((np + 3) & 63))];
    *(ushort4*)(vt + base + (size_t)c * 512 + np) = o;
  }
}

// ---------------- windowed attention: XCD-swizzled grid, 128-key chunks ----------------
// grid: 1536 blocks, blk = qblk*192 + whi  (same whi -> same blk%8 -> same XCD L2)
// 4 waves each own 16 q-rows; online softmax once per 128 keys
__global__ __launch_bounds__(256) void attn_win(const u16* __restrict__ Qp,
    const u16* __restrict__ Kp, const u16* __restrict__ vt,
    const float* __restrict__ rpd, const float* __restrict__ rph,
    const float* __restrict__ rpw, u16* __restrict__ out) {
  int blk = blockIdx.x;
  int whi = blk % WHN, qblk = blk / WHN;
  int wi = whi / NHEADS, hh = whi % NHEADS;
  int tid = threadIdx.x;
  int wave = tid >> 6, lane = tid & 63;
  int g = lane >> 4, c15 = lane & 15;
  int n0 = qblk * 64 + wave * 16;
  __shared__ float rel_s[4][3][16][8];
  __shared__ __align__(16) u16 p_lds[4][16][136];  // row stride 272B (16B-aligned)
  const u16* qbase = Qp + (size_t)whi * WHSZ;
  const u16* kbase = Kp + (size_t)whi * WHSZ;
  const u16* vbase = vt + (size_t)whi * WHSZ;
  // Q A-fragments (rows n0..n0+15, k split 0..31 / 32..63)
  const u16* qb = qbase + (size_t)(n0 + c15) * 64;
  s16x8 a0 = *(const s16x8*)(qb + g * 8);
  s16x8 a1 = *(const s16x8*)(qb + 32 + g * 8);
  // rel-pos tables: rel_s[w][axis][r][kx] = dot(q[n0+r], rel_pos_axis[coord-kx+7])
  for (int e = lane; e < 384; e += 64) {
    int ti = e >> 7, rr = (e >> 3) & 15, kx = e & 7;
    int n = n0 + rr;
    int coord = (ti == 0) ? (n >> 6) : (ti == 1) ? ((n >> 3) & 7) : (n & 7);
    const float* rp = ((ti == 0) ? rpd : (ti == 1) ? rph : rpw) + (coord - kx + 7) * 64;
    const u16* qr = qbase + (size_t)n * 64;
    float s = 0.f;
    for (int cb = 0; cb < 64; cb += 8) {
      s16x8 qv = *(const s16x8*)(qr + cb);
      #pragma unroll
      for (int u = 0; u < 8; u++) s += bf2f((u16)qv[u]) * rp[cb + u];
    }
    rel_s[wave][ti][rr][kx] = s;
  }
  // rel_s / p_lds are wave-private; same-wave DS ops are in-order -> asm fence
  asm volatile("s_waitcnt lgkmcnt(0)" ::: "memory");
  __builtin_amdgcn_sched_barrier(0);
  float m_[4], l_[4];
  f32x4 o_[4] = {};
  #pragma unroll
  for (int j = 0; j < 4; j++) { m_[j] = -1e30f; l_[j] = 0.f; }
  for (int kc = 0; kc < 512; kc += 128) {
    // ---- QK^T for 128 keys: S in registers (8 tiles x 4 rows) ----
    f32x4 s[8];
    #pragma unroll
    for (int cc = 0; cc < 8; cc++) {
      const u16* kb = kbase + (size_t)(kc + cc * 16 + c15) * 64;
      s16x8 k0 = *(const s16x8*)(kb + g * 8);
      s16x8 k1 = *(const s16x8*)(kb + 32 + g * 8);
      f32x4 t = {0.f, 0.f, 0.f, 0.f};
      t = mfma16(a0, k0, t);
      s[cc] = mfma16(a1, k1, t);
    }
    // ---- scale + rel-pos (in place) ----
    #pragma unroll
    for (int cc = 0; cc < 8; cc++) {
      int kt = kc + cc * 16 + c15;
      int kd = kt >> 6, kh = (kt >> 3) & 7, kw = kt & 7;
      #pragma unroll
      for (int j = 0; j < 4; j++) {
        int r = g * 4 + j;
        s[cc][j] = s[cc][j] * QK_SCALE + rel_s[wave][0][r][kd] +
                   rel_s[wave][1][r][kh] + rel_s[wave][2][r][kw];
      }
    }
    // ---- online softmax, one update per 128 keys ----
    #pragma unroll
    for (int j = 0; j < 4; j++) {
      float mx = fmaxf(fmaxf(fmaxf(s[0][j], s[1][j]), fmaxf(s[2][j], s[3][j])),
                       fmaxf(fmaxf(s[4][j], s[5][j]), fmaxf(s[6][j], s[7][j])));
      #pragma unroll
      for (int msk = 1; msk < 16; msk <<= 1) mx = fmaxf(mx, __shfl_xor(mx, msk));
      float mn = fmaxf(m_[j], mx);
      float corr = __expf(m_[j] - mn);
      float p[8], rs = 0.f;
      #pragma unroll
      for (int cc = 0; cc < 8; cc++) { p[cc] = __expf(s[cc][j] - mn); rs += p[cc]; }
      #pragma unroll
      for (int msk = 1; msk < 16; msk <<= 1) rs += __shfl_xor(rs, msk);
      l_[j] = l_[j] * corr + rs;
      m_[j] = mn;
      #pragma unroll
      for (int cf = 0; cf < 4; cf++) o_[cf][j] *= corr;
      #pragma unroll
      for (int cc = 0; cc < 8; cc++)
        p_lds[wave][g * 4 + j][cc * 16 + c15] = f2bf(p[cc]);
    }
    asm volatile("s_waitcnt lgkmcnt(0)" ::: "memory");
    __builtin_amdgcn_sched_barrier(0);
    // ---- PV: P (16x128) x V^T (128x64) ----
    s16x8 pa[4];
    #pragma unroll
    for (int ks = 0; ks < 4; ks++)
      pa[ks] = *(const s16x8*)&p_lds[wave][c15][ks * 32 + g * 8];
    const u16* vb = vbase + kc + g * 8;
    #pragma unroll
    for (int cf = 0; cf < 4; cf++) {
      const u16* vr = vb + (size_t)(cf * 16 + c15) * 512;
      #pragma unroll
      for (int ks = 0; ks < 4; ks++)
        o_[cf] = mfma16(pa[ks], *(const s16x8*)(vr + ks * 32), o_[cf]);
    }
    __builtin_amdgcn_sched_barrier(0);
  }
  #pragma unroll
  for (int j = 0; j < 4; j++) l_[j] = 1.0f / l_[j];
  #pragma unroll
  for (int j = 0; j < 4; j++) {
    int t = tok_of(wi, n0 + g * 4 + j);
    u16* orow = out + (size_t)t * NDIM + hh * 64;
    #pragma unroll
    for (int cf = 0; cf < 4; cf++) orow[cf * 16 + c15] = f2bf(o_[cf][j] * l_[j]);
  }
}

extern "C" void kernel_launch(void* const* d_in, const int* in_sizes, int n_in,
                              void* d_out, int out_size, void* d_ws, size_t ws_size,
                              hipStream_t stream) {
  const float* x     = (const float*)d_in[0];
  const float* ln1_g = (const float*)d_in[1];
  const float* ln1_b = (const float*)d_in[2];
  const float* qkv_w = (const float*)d_in[3];
  const float* qkv_b = (const float*)d_in[4];
  const float* rpd   = (const float*)d_in[5];
  const float* rph   = (const float*)d_in[6];
  const float* rpw   = (const float*)d_in[7];
  const float* proj_w = (const float*)d_in[8];
  const float* proj_b = (const float*)d_in[9];
  const float* aa1_w = (const float*)d_in[10];
  const float* aa1_b = (const float*)d_in[11];
  const float* aa2_w = (const float*)d_in[12];
  const float* aa2_b = (const float*)d_in[13];
  const float* ln2_g = (const float*)d_in[14];
  const float* ln2_b = (const float*)d_in[15];
  const float* mlp1_w = (const float*)d_in[16];
  const float* mlp1_b = (const float*)d_in[17];
  const float* mlp2_w = (const float*)d_in[18];
  const float* mlp2_b = (const float*)d_in[19];
  const float* ma1_w = (const float*)d_in[20];
  const float* ma1_b = (const float*)d_in[21];
  const float* ma2_w = (const float*)d_in[22];
  const float* ma2_b = (const float*)d_in[23];
  float* out = (float*)d_out;
  char* ws = (char*)d_ws;

  // arena (explicit lifetimes; total ~157 MB)
  u16* wqkv  = (u16*)(ws + 0);          // 3538944 B
  u16* wproj = (u16*)(ws + 3538944);    // 1179648
  u16* wmlp1 = (u16*)(ws + 4718592);    // 4718592
  u16* wmlp2 = (u16*)(ws + 9437184);    // 4718592
  u16* waa1  = (u16*)(ws + 14155776);   // 294912
  u16* waa2  = (u16*)(ws + 14450688);   // 294912
  u16* wma1  = (u16*)(ws + 14745600);   // 294912
  u16* wma2  = (u16*)(ws + 15040512);   // 294912
  u16* h1    = (u16*)(ws + 15335424);   // 12.58 MB: LN1 out, then reused as attn_out
  u16* attno = h1;
  u16* qkvp  = (u16*)(ws + 27918336);   // 37.75 MB: packed Qp|Kp|Vp, then p_f32 + p_bf16
  float* p_f = (float*)(ws + 27918336);
  u16* p_bf  = (u16*)(ws + 53084160);
  u16* vtp   = (u16*)(ws + 65667072);   // 12.58 MB: V_t, then hn
  u16* hn    = vtp;
  float* h_f = (float*)(ws + 78249984); // 25.17 MB
  u16* ah    = (u16*)(ws + 103415808);  // adapter hidden, then mlp hidden (50.33 MB)
  u16* mlph  = ah;
  u16* mah   = (u16*)(ws + 153747456);  // 3.15 MB
  (void)ws_size; (void)in_sizes; (void)n_in; (void)out_size;

  u16* Qp = qkvp;
  u16* Kp = qkvp + (size_t)WHN * WHSZ;
  u16* Vp = qkvp + 2 * (size_t)WHN * WHSZ;

  WConv wc;
  wc.src[0] = qkv_w;  wc.dst[0] = wqkv;  wc.n[0] = 2304 * 768;
  wc.src[1] = proj_w; wc.dst[1] = wproj; wc.n[1] = 768 * 768;
  wc.src[2] = mlp1_w; wc.dst[2] = wmlp1; wc.n[2] = 3072 * 768;
  wc.src[3] = mlp2_w; wc.dst[3] = wmlp2; wc.n[3] = 768 * 3072;
  wc.src[4] = aa1_w;  wc.dst[4] = waa1;  wc.n[4] = 192 * 768;
  wc.src[5] = aa2_w;  wc.dst[5] = waa2;  wc.n[5] = 768 * 192;
  wc.src[6] = ma1_w;  wc.dst[6] = wma1;  wc.n[6] = 192 * 768;
  wc.src[7] = ma2_w;  wc.dst[7] = wma2;  wc.n[7] = 768 * 192;
  conv_weights<<<1024, 256, 0, stream>>>(wc);

  ln_bf16<<<TOK, 256, 0, stream>>>(x, ln1_g, ln1_b, h1);
  gemm_bf16<128, 6><<<dim3(64, 18), 256, 0, stream>>>(h1, wqkv, qkv_b, TOK, 2304, 768,
                                                      qkvp, nullptr, nullptr, nullptr);
  repack_v<<<192, 256, 0, stream>>>(Vp, vtp);
  attn_win<<<1536, 256, 0, stream>>>(Qp, Kp, vtp, rpd, rph, rpw, attno);
  gemm_bf16<128, 1><<<dim3(64, 6), 256, 0, stream>>>(attno, wproj, proj_b, TOK, 768, 768,
                                                     p_bf, p_f, nullptr, nullptr);
  gemm_bf16<64, 2><<<dim3(64, 3), 256, 0, stream>>>(p_bf, waa1, aa1_b, TOK, 192, 768,
                                                    ah, nullptr, nullptr, nullptr);
  gemm_bf16<128, 3><<<dim3(64, 6), 256, 0, stream>>>(ah, waa2, aa2_b, TOK, 768, 192,
                                                     nullptr, h_f, x, p_f);
  ln_bf16<<<TOK, 256, 0, stream>>>(h_f, ln2_g, ln2_b, hn);
  gemm_bf16<128, 2><<<dim3(64, 24), 256, 0, stream>>>(hn, wmlp1, mlp1_b, TOK, 3072, 768,
                                                      mlph, nullptr, nullptr, nullptr);
  gemm_bf16<128, 4><<<dim3(64, 6), 256, 0, stream>>>(mlph, wmlp2, mlp2_b, TOK, 768, 3072,
                                                     nullptr, out, h_f, nullptr);
  gemm_bf16<64, 2><<<dim3(64, 3), 256, 0, stream>>>(hn, wma1, ma1_b, TOK, 192, 768,
                                                    mah, nullptr, nullptr, nullptr);
  gemm_bf16<128, 5><<<dim3(64, 6), 256, 0, stream>>>(mah, wma2, ma2_b, TOK, 768, 192,
                                                     nullptr, out, out, nullptr);
}

// Round 4
// 472.868 us; speedup vs baseline: 1.0938x; 1.0938x over previous
//
#include <hip/hip_runtime.h>

typedef unsigned short u16;
typedef __attribute__((ext_vector_type(4))) float f32x4;
typedef __attribute__((ext_vector_type(8))) short s16x8;

#define TOK 8192
#define NDIM 768
#define NHEADS 12
#define QK_SCALE 0.125f
#define WHN 192            // window-heads
#define WHSZ 32768         // 512*64 elements per window-head plane

__device__ __forceinline__ u16 f2bf(float f) {
  union { float f; unsigned u; } x; x.f = f;
  unsigned r = x.u + 0x7fffu + ((x.u >> 16) & 1u);
  return (u16)(r >> 16);
}
__device__ __forceinline__ float bf2f(u16 u) {
  union { unsigned u; float f; } x; x.u = ((unsigned)u) << 16;
  return x.f;
}
__device__ __forceinline__ float gelu_f(float v) {
  return 0.5f * v * (1.0f + erff(v * 0.70710678118654752f));
}
__device__ __forceinline__ f32x4 mfma16(s16x8 a, s16x8 b, f32x4 c) {
  return __builtin_amdgcn_mfma_f32_16x16x32_bf16(a, b, c, 0, 0, 0);
}
__device__ __forceinline__ void glds16(const u16* g, u16* l) {
  __builtin_amdgcn_global_load_lds(
      (const __attribute__((address_space(1))) unsigned int*)g,
      (__attribute__((address_space(3))) unsigned int*)l, 16, 0, 0);
}
// window (wi in [0,16), n in [0,512)) -> flat spatial token index
__device__ __forceinline__ int tok_of(int wi, int n) {
  int b = wi >> 3;
  int d = (((wi >> 2) & 1) << 3) | (n >> 6);
  int h = (((wi >> 1) & 1) << 3) | ((n >> 3) & 7);
  int w = ((wi & 1) << 3) | (n & 7);
  return (b << 12) | (d << 8) | (h << 4) | w;
}

// ---------------- weight fp32 -> bf16 ----------------
struct WConv {
  const float* src[8];
  u16* dst[8];
  int n[8];
};
__global__ __launch_bounds__(256) void conv_weights(WConv a) {
  int stride = gridDim.x * blockDim.x;
  int t0 = blockIdx.x * blockDim.x + threadIdx.x;
  for (int s = 0; s < 8; s++) {
    const float4* src = (const float4*)a.src[s];
    u16* dst = a.dst[s];
    int n4 = a.n[s] >> 2;
    for (int i = t0; i < n4; i += stride) {
      float4 v = src[i];
      ushort4 o;
      o.x = f2bf(v.x); o.y = f2bf(v.y); o.z = f2bf(v.z); o.w = f2bf(v.w);
      *(ushort4*)(dst + 4 * (size_t)i) = o;
    }
  }
}

// ---------------- LayerNorm (fp32 in -> bf16 out) ----------------
__global__ __launch_bounds__(256) void ln_bf16(const float* __restrict__ in,
    const float* __restrict__ gamma, const float* __restrict__ beta,
    u16* __restrict__ out) {
  const int row = blockIdx.x;
  const int tid = threadIdx.x;
  const float* xr = in + (size_t)row * NDIM;
  float v0 = xr[tid], v1 = xr[tid + 256], v2 = xr[tid + 512];
  float s = v0 + v1 + v2;
  float q = v0 * v0 + v1 * v1 + v2 * v2;
  for (int o = 32; o; o >>= 1) { s += __shfl_down(s, o); q += __shfl_down(q, o); }
  __shared__ float ss[4], sq[4];
  int wave = tid >> 6, lane = tid & 63;
  if (lane == 0) { ss[wave] = s; sq[wave] = q; }
  __syncthreads();
  s = ss[0] + ss[1] + ss[2] + ss[3];
  q = sq[0] + sq[1] + sq[2] + sq[3];
  float mean = s * (1.0f / 768.0f);
  float var = q * (1.0f / 768.0f) - mean * mean;
  float rstd = rsqrtf(var + 1e-5f);
  u16* orow = out + (size_t)row * NDIM;
  float v[3] = {v0, v1, v2};
  #pragma unroll
  for (int i = 0; i < 3; i++) {
    int c = tid + i * 256;
    orow[c] = f2bf((v[i] - mean) * rstd * gamma[c] + beta[c]);
  }
}

// ---------------- GEMM: C[M,N] = A[M,K](bf16) * W[N,K]^T(bf16) + bias, epilogues ----------------
// EPI 0: bf16 store; 1: f32+bf16 store; 2: gelu->bf16; 3: h=add1+add2+v ->f32;
// EPI 4: out=add1+v ->f32; 5: out=add1+0.5v ->f32; 6: packed QKV store per window-head
template<int BN, int EPI>
__global__ __launch_bounds__(256) void gemm_bf16(
    const u16* __restrict__ A, const u16* __restrict__ W,
    const float* __restrict__ bias, int M, int N, int K,
    u16* __restrict__ obf, float* __restrict__ of,
    const float* __restrict__ add1, const float* __restrict__ add2) {
  constexpr int BM = 128, BK = 32;
  constexpr int WN = BN / 2;
  constexpr int MF = 4, NF = WN / 16;
  constexpr int ACH = BM * BK / (8 * 256);  // 16B chunks per thread for A
  constexpr int BCH = BN * BK / (8 * 256);
  __shared__ __align__(16) u16 As[BM * BK];
  __shared__ __align__(16) u16 Bs[BN * BK];
  const int bm = blockIdx.x, bn = blockIdx.y;
  const int tid = threadIdx.x;
  const int wave = tid >> 6, lane = tid & 63;
  const int wr = wave >> 1, wc = wave & 1;
  const int g = lane >> 4, c15 = lane & 15;
  f32x4 acc[MF][NF] = {};
  const u16* Ab = A + (size_t)(bm * BM) * K;
  const u16* Wb = W + (size_t)(bn * BN) * K;
  for (int k0 = 0; k0 < K; k0 += BK) {
    #pragma unroll
    for (int i = 0; i < ACH; i++) {
      int L = i * 256 + tid;
      glds16(Ab + (size_t)(L >> 2) * K + k0 + (L & 3) * 8, &As[L * 8]);
    }
    #pragma unroll
    for (int i = 0; i < BCH; i++) {
      int L = i * 256 + tid;
      glds16(Wb + (size_t)(L >> 2) * K + k0 + (L & 3) * 8, &Bs[L * 8]);
    }
    __syncthreads();
    s16x8 af[MF], bfr[NF];
    #pragma unroll
    for (int mi = 0; mi < MF; mi++)
      af[mi] = *(const s16x8*)&As[(wr * 64 + mi * 16 + c15) * BK + g * 8];
    #pragma unroll
    for (int ni = 0; ni < NF; ni++)
      bfr[ni] = *(const s16x8*)&Bs[(wc * WN + ni * 16 + c15) * BK + g * 8];
    #pragma unroll
    for (int mi = 0; mi < MF; mi++)
      #pragma unroll
      for (int ni = 0; ni < NF; ni++)
        acc[mi][ni] = mfma16(af[mi], bfr[ni], acc[mi][ni]);
    __syncthreads();
  }
  #pragma unroll
  for (int mi = 0; mi < MF; mi++) {
    #pragma unroll
    for (int ni = 0; ni < NF; ni++) {
      int col = bn * BN + wc * WN + ni * 16 + c15;
      float bv = bias[col];
      #pragma unroll
      for (int j = 0; j < 4; j++) {
        int row = bm * BM + wr * 64 + mi * 16 + g * 4 + j;
        size_t idx = (size_t)row * N + col;
        float v = acc[mi][ni][j] + bv;
        if (EPI == 0) {
          obf[idx] = f2bf(v);
        } else if (EPI == 1) {
          of[idx] = v; obf[idx] = f2bf(v);
        } else if (EPI == 2) {
          obf[idx] = f2bf(gelu_f(v));
        } else if (EPI == 3) {
          of[idx] = add1[idx] + add2[idx] + v;
        } else if (EPI == 4) {
          of[idx] = add1[idx] + v;
        } else if (EPI == 5) {
          of[idx] = add1[idx] + 0.5f * v;
        } else if (EPI == 6) {
          // packed QKV: seg 0/1/2 -> Qp/Kp/Vp [whi][n][64]
          int seg = col >= 1536 ? 2 : (col >= 768 ? 1 : 0);
          int cc_ = col - seg * 768;
          int hh = cc_ >> 6, c = cc_ & 63;
          int t = row;
          int b = t >> 12, d = (t >> 8) & 15, hy = (t >> 4) & 15, wx = t & 15;
          int wi = (b << 3) | ((d >> 3) << 2) | ((hy >> 3) << 1) | (wx >> 3);
          int n = ((d & 7) << 6) | ((hy & 7) << 3) | (wx & 7);
          obf[(size_t)seg * (WHN * WHSZ) +
              ((size_t)(wi * NHEADS + hh) * 512 + n) * 64 + c] = f2bf(v);
        }
      }
    }
  }
}

// ---------------- transpose Vp[whi][n][c] -> Vt[whi][c][n] ----------------
__global__ __launch_bounds__(256) void repack_v(const u16* __restrict__ vp,
                                                u16* __restrict__ vt) {
  int whi = blockIdx.x;
  __shared__ u16 Vs[512 * 64];  // XOR-swizzled: slot(n,c) = n*64 + (c ^ (n&63))
  int tid = threadIdx.x;
  const u16* src = vp + (size_t)whi * WHSZ;
  for (int idx = tid; idx < 512 * 64; idx += 256) {
    int n = idx >> 6, c = idx & 63;
    Vs[(n << 6) | (c ^ (n & 63))] = src[idx];
  }
  __syncthreads();
  size_t base = (size_t)whi * WHSZ;
  #pragma unroll 1
  for (int i = 0; i < 32; i++) {
    int idx4 = tid + i * 256;  // 0..8191
    int c = idx4 >> 7, np = (idx4 & 127) << 2;
    ushort4 o;
    o.x = Vs[((np + 0) << 6) | (c ^ ((np + 0) & 63))];
    o.y = Vs[((np + 1) << 6) | (c ^ ((np + 1) & 63))];
    o.z = Vs[((np + 2) << 6) | (c ^ ((np + 2) & 63))];
    o.w = Vs[((np + 3) << 6) | (c ^ ((np + 3) & 63))];
    *(ushort4*)(vt + base + (size_t)c * 512 + np) = o;
  }
}

// ---------------- windowed attention: LDS-staged K/V, double-buffered ----------------
// grid: 1536 blocks, blk = qblk*192 + whi (same whi -> same XCD L2)
// 4 waves x 16 q-rows; 64-key chunks; K/V staged via global_load_lds w/ XOR swizzle
__global__ __launch_bounds__(256) void attn_win(const u16* __restrict__ Qp,
    const u16* __restrict__ Kp, const u16* __restrict__ vt,
    const float* __restrict__ rpd, const float* __restrict__ rph,
    const float* __restrict__ rpw, u16* __restrict__ out) {
  int blk = blockIdx.x;
  int whi = blk % WHN, qblk = blk / WHN;
  int wi = whi / NHEADS, hh = whi % NHEADS;
  int tid = threadIdx.x;
  int wave = tid >> 6, lane = tid & 63;
  int g = lane >> 4, c15 = lane & 15;
  int n0 = qblk * 64 + wave * 16;
  // LDS: K/V chunk double buffers (8KB each), rel tables, P staging
  __shared__ __align__(16) u16 Ks[2][4096];    // 64 rows x 64 u16, 16B-unit XOR-swizzled
  __shared__ __align__(16) u16 Vs[2][4096];    // 64 c-rows x 64 keys, same swizzle
  __shared__ float rel_s[4][3][16][8];
  __shared__ __align__(16) u16 p_lds[4][16][72];  // row stride 144B
  const u16* qbase = Qp + (size_t)whi * WHSZ;
  const u16* kbase = Kp + (size_t)whi * WHSZ;
  const u16* vbase = vt + (size_t)whi * WHSZ;

  // stage one 64-key chunk of K and V into LDS buffer `buf`
  // LDS layout: row r (0..63), 8 units of 16B; unit u stored at slot (u ^ (r&7))
  // achieved by pre-swizzling the per-lane GLOBAL source address (dest stays linear)
  auto stage = [&](int kc, int buf) {
    #pragma unroll
    for (int i = 0; i < 2; i++) {
      int seg = wave * 2048 + i * 1024 + lane * 16;  // byte offset in 8KB buffer
      int r = seg >> 7, u = (seg >> 4) & 7;
      int su = (u ^ (r & 7)) << 3;                   // swizzled unit, u16 offset
      glds16(kbase + (size_t)(kc + r) * 64 + su, &Ks[buf][seg >> 1]);
      glds16(vbase + (size_t)r * 512 + kc + su, &Vs[buf][seg >> 1]);
    }
  };

  stage(0, 0);  // chunk 0 -> buf 0 (latency overlaps prolog below)

  // Q A-fragments (rows n0..n0+15, k split 0..31 / 32..63)
  const u16* qb = qbase + (size_t)(n0 + c15) * 64;
  s16x8 a0 = *(const s16x8*)(qb + g * 8);
  s16x8 a1 = *(const s16x8*)(qb + 32 + g * 8);
  // rel-pos tables: rel_s[w][axis][r][kx] = dot(q[n0+r], rel_pos_axis[coord-kx+7])
  for (int e = lane; e < 384; e += 64) {
    int ti = e >> 7, rr = (e >> 3) & 15, kx = e & 7;
    int n = n0 + rr;
    int coord = (ti == 0) ? (n >> 6) : (ti == 1) ? ((n >> 3) & 7) : (n & 7);
    const float* rp = ((ti == 0) ? rpd : (ti == 1) ? rph : rpw) + (coord - kx + 7) * 64;
    const u16* qr = qbase + (size_t)n * 64;
    float s = 0.f;
    for (int cb = 0; cb < 64; cb += 8) {
      s16x8 qv = *(const s16x8*)(qr + cb);
      const float4* rp4 = (const float4*)(rp + cb);
      float4 rA = rp4[0], rB = rp4[1];
      s += bf2f((u16)qv[0]) * rA.x + bf2f((u16)qv[1]) * rA.y +
           bf2f((u16)qv[2]) * rA.z + bf2f((u16)qv[3]) * rA.w +
           bf2f((u16)qv[4]) * rB.x + bf2f((u16)qv[5]) * rB.y +
           bf2f((u16)qv[6]) * rB.z + bf2f((u16)qv[7]) * rB.w;
    }
    rel_s[wave][ti][rr][kx] = s;
  }
  __syncthreads();  // chunk0 staged + rel_s ready

  // hoist rel_h/rel_w into registers:
  // kw = c15&7 (lane-const); kh = (cc*2 + (c15>>3)) & 7 (kc-independent)
  float rbias[4][4];  // [cc][j] = rel_h + rel_w
  #pragma unroll
  for (int j = 0; j < 4; j++) {
    float rw_ = rel_s[wave][2][g * 4 + j][c15 & 7];
    #pragma unroll
    for (int cc = 0; cc < 4; cc++)
      rbias[cc][j] = rel_s[wave][1][g * 4 + j][(cc * 2 + (c15 >> 3)) & 7] + rw_;
  }

  float m_[4], l_[4];
  f32x4 o_[4] = {};
  #pragma unroll
  for (int j = 0; j < 4; j++) { m_[j] = -1e30f; l_[j] = 0.f; }

  for (int c = 0; c < 8; c++) {
    int buf = c & 1;
    int kc = c * 64;
    if (c < 7) stage(kc + 64, buf ^ 1);  // prefetch next chunk (drains at barrier)
    // ---- QK^T: 64 keys, S in registers ----
    f32x4 s[4];
    #pragma unroll
    for (int cc = 0; cc < 4; cc++) {
      int r = cc * 16 + c15;
      const u16* kr = &Ks[buf][r * 64];
      s16x8 k0 = *(const s16x8*)(kr + ((g ^ (r & 7)) << 3));
      s16x8 k1 = *(const s16x8*)(kr + (((4 + g) ^ (r & 7)) << 3));
      f32x4 t = {0.f, 0.f, 0.f, 0.f};
      t = mfma16(a0, k0, t);
      s[cc] = mfma16(a1, k1, t);
    }
    // ---- scale + rel-pos (rel_d uniform per chunk; rest in registers) ----
    float rdv[4];
    #pragma unroll
    for (int j = 0; j < 4; j++) rdv[j] = rel_s[wave][0][g * 4 + j][kc >> 6];
    #pragma unroll
    for (int cc = 0; cc < 4; cc++)
      #pragma unroll
      for (int j = 0; j < 4; j++)
        s[cc][j] = s[cc][j] * QK_SCALE + (rdv[j] + rbias[cc][j]);
    // ---- online softmax (one update per 64 keys) ----
    #pragma unroll
    for (int j = 0; j < 4; j++) {
      float mx = fmaxf(fmaxf(s[0][j], s[1][j]), fmaxf(s[2][j], s[3][j]));
      #pragma unroll
      for (int msk = 1; msk < 16; msk <<= 1) mx = fmaxf(mx, __shfl_xor(mx, msk));
      float mn = fmaxf(m_[j], mx);
      float corr = __expf(m_[j] - mn);
      float p[4], rs = 0.f;
      #pragma unroll
      for (int cc = 0; cc < 4; cc++) { p[cc] = __expf(s[cc][j] - mn); rs += p[cc]; }
      #pragma unroll
      for (int msk = 1; msk < 16; msk <<= 1) rs += __shfl_xor(rs, msk);
      l_[j] = l_[j] * corr + rs;
      m_[j] = mn;
      #pragma unroll
      for (int cf = 0; cf < 4; cf++) o_[cf][j] *= corr;
      #pragma unroll
      for (int cc = 0; cc < 4; cc++)
        p_lds[wave][g * 4 + j][cc * 16 + c15] = f2bf(p[cc]);
    }
    // wave-private P handoff (rule #18 fence)
    asm volatile("s_waitcnt lgkmcnt(0)" ::: "memory");
    __builtin_amdgcn_sched_barrier(0);
    // ---- PV: P (16x64) x V^T (64x64) ----
    s16x8 pa0 = *(const s16x8*)&p_lds[wave][c15][g * 8];
    s16x8 pa1 = *(const s16x8*)&p_lds[wave][c15][32 + g * 8];
    #pragma unroll
    for (int cf = 0; cf < 4; cf++) {
      int cv = cf * 16 + c15;
      const u16* vr = &Vs[buf][cv * 64];
      o_[cf] = mfma16(pa0, *(const s16x8*)(vr + ((g ^ (cv & 7)) << 3)), o_[cf]);
      o_[cf] = mfma16(pa1, *(const s16x8*)(vr + (((4 + g) ^ (cv & 7)) << 3)), o_[cf]);
    }
    __syncthreads();  // next chunk staged; all waves done with buf
  }
  #pragma unroll
  for (int j = 0; j < 4; j++) l_[j] = 1.0f / l_[j];
  #pragma unroll
  for (int j = 0; j < 4; j++) {
    int t = tok_of(wi, n0 + g * 4 + j);
    u16* orow = out + (size_t)t * NDIM + hh * 64;
    #pragma unroll
    for (int cf = 0; cf < 4; cf++) orow[cf * 16 + c15] = f2bf(o_[cf][j] * l_[j]);
  }
}

extern "C" void kernel_launch(void* const* d_in, const int* in_sizes, int n_in,
                              void* d_out, int out_size, void* d_ws, size_t ws_size,
                              hipStream_t stream) {
  const float* x     = (const float*)d_in[0];
  const float* ln1_g = (const float*)d_in[1];
  const float* ln1_b = (const float*)d_in[2];
  const float* qkv_w = (const float*)d_in[3];
  const float* qkv_b = (const float*)d_in[4];
  const float* rpd   = (const float*)d_in[5];
  const float* rph   = (const float*)d_in[6];
  const float* rpw   = (const float*)d_in[7];
  const float* proj_w = (const float*)d_in[8];
  const float* proj_b = (const float*)d_in[9];
  const float* aa1_w = (const float*)d_in[10];
  const float* aa1_b = (const float*)d_in[11];
  const float* aa2_w = (const float*)d_in[12];
  const float* aa2_b = (const float*)d_in[13];
  const float* ln2_g = (const float*)d_in[14];
  const float* ln2_b = (const float*)d_in[15];
  const float* mlp1_w = (const float*)d_in[16];
  const float* mlp1_b = (const float*)d_in[17];
  const float* mlp2_w = (const float*)d_in[18];
  const float* mlp2_b = (const float*)d_in[19];
  const float* ma1_w = (const float*)d_in[20];
  const float* ma1_b = (const float*)d_in[21];
  const float* ma2_w = (const float*)d_in[22];
  const float* ma2_b = (const float*)d_in[23];
  float* out = (float*)d_out;
  char* ws = (char*)d_ws;

  // arena (explicit lifetimes; total ~157 MB)
  u16* wqkv  = (u16*)(ws + 0);          // 3538944 B
  u16* wproj = (u16*)(ws + 3538944);    // 1179648
  u16* wmlp1 = (u16*)(ws + 4718592);    // 4718592
  u16* wmlp2 = (u16*)(ws + 9437184);    // 4718592
  u16* waa1  = (u16*)(ws + 14155776);   // 294912
  u16* waa2  = (u16*)(ws + 14450688);   // 294912
  u16* wma1  = (u16*)(ws + 14745600);   // 294912
  u16* wma2  = (u16*)(ws + 15040512);   // 294912
  u16* h1    = (u16*)(ws + 15335424);   // 12.58 MB: LN1 out, then reused as attn_out
  u16* attno = h1;
  u16* qkvp  = (u16*)(ws + 27918336);   // 37.75 MB: packed Qp|Kp|Vp, then p_f32 + p_bf16
  float* p_f = (float*)(ws + 27918336);
  u16* p_bf  = (u16*)(ws + 53084160);
  u16* vtp   = (u16*)(ws + 65667072);   // 12.58 MB: V_t, then hn
  u16* hn    = vtp;
  float* h_f = (float*)(ws + 78249984); // 25.17 MB
  u16* ah    = (u16*)(ws + 103415808);  // adapter hidden, then mlp hidden (50.33 MB)
  u16* mlph  = ah;
  u16* mah   = (u16*)(ws + 153747456);  // 3.15 MB
  (void)ws_size; (void)in_sizes; (void)n_in; (void)out_size;

  u16* Qp = qkvp;
  u16* Kp = qkvp + (size_t)WHN * WHSZ;
  u16* Vp = qkvp + 2 * (size_t)WHN * WHSZ;

  WConv wc;
  wc.src[0] = qkv_w;  wc.dst[0] = wqkv;  wc.n[0] = 2304 * 768;
  wc.src[1] = proj_w; wc.dst[1] = wproj; wc.n[1] = 768 * 768;
  wc.src[2] = mlp1_w; wc.dst[2] = wmlp1; wc.n[2] = 3072 * 768;
  wc.src[3] = mlp2_w; wc.dst[3] = wmlp2; wc.n[3] = 768 * 3072;
  wc.src[4] = aa1_w;  wc.dst[4] = waa1;  wc.n[4] = 192 * 768;
  wc.src[5] = aa2_w;  wc.dst[5] = waa2;  wc.n[5] = 768 * 192;
  wc.src[6] = ma1_w;  wc.dst[6] = wma1;  wc.n[6] = 192 * 768;
  wc.src[7] = ma2_w;  wc.dst[7] = wma2;  wc.n[7] = 768 * 192;
  conv_weights<<<1024, 256, 0, stream>>>(wc);

  ln_bf16<<<TOK, 256, 0, stream>>>(x, ln1_g, ln1_b, h1);
  gemm_bf16<128, 6><<<dim3(64, 18), 256, 0, stream>>>(h1, wqkv, qkv_b, TOK, 2304, 768,
                                                      qkvp, nullptr, nullptr, nullptr);
  repack_v<<<192, 256, 0, stream>>>(Vp, vtp);
  attn_win<<<1536, 256, 0, stream>>>(Qp, Kp, vtp, rpd, rph, rpw, attno);
  gemm_bf16<128, 1><<<dim3(64, 6), 256, 0, stream>>>(attno, wproj, proj_b, TOK, 768, 768,
                                                     p_bf, p_f, nullptr, nullptr);
  gemm_bf16<64, 2><<<dim3(64, 3), 256, 0, stream>>>(p_bf, waa1, aa1_b, TOK, 192, 768,
                                                    ah, nullptr, nullptr, nullptr);
  gemm_bf16<128, 3><<<dim3(64, 6), 256, 0, stream>>>(ah, waa2, aa2_b, TOK, 768, 192,
                                                     nullptr, h_f, x, p_f);
  ln_bf16<<<TOK, 256, 0, stream>>>(h_f, ln2_g, ln2_b, hn);
  gemm_bf16<128, 2><<<dim3(64, 24), 256, 0, stream>>>(hn, wmlp1, mlp1_b, TOK, 3072, 768,
                                                      mlph, nullptr, nullptr, nullptr);
  gemm_bf16<128, 4><<<dim3(64, 6), 256, 0, stream>>>(mlph, wmlp2, mlp2_b, TOK, 768, 3072,
                                                     nullptr, out, h_f, nullptr);
  gemm_bf16<64, 2><<<dim3(64, 3), 256, 0, stream>>>(hn, wma1, ma1_b, TOK, 192, 768,
                                                    mah, nullptr, nullptr, nullptr);
  gemm_bf16<128, 5><<<dim3(64, 6), 256, 0, stream>>>(mah, wma2, ma2_b, TOK, 768, 192,
                                                     nullptr, out, out, nullptr);
}

// Round 5
// 448.389 us; speedup vs baseline: 1.1535x; 1.0546x over previous
//
#include <hip/hip_runtime.h>

typedef unsigned short u16;
typedef __attribute__((ext_vector_type(4))) float f32x4;
typedef __attribute__((ext_vector_type(8))) short s16x8;

#define TOK 8192
#define NDIM 768
#define NHEADS 12
#define QK_SCALE 0.125f
#define WHN 192            // window-heads
#define WHSZ 32768         // 512*64 elements per window-head plane

__device__ __forceinline__ u16 f2bf(float f) {
  union { float f; unsigned u; } x; x.f = f;
  unsigned r = x.u + 0x7fffu + ((x.u >> 16) & 1u);
  return (u16)(r >> 16);
}
__device__ __forceinline__ float bf2f(u16 u) {
  union { unsigned u; float f; } x; x.u = ((unsigned)u) << 16;
  return x.f;
}
__device__ __forceinline__ float gelu_f(float v) {
  return 0.5f * v * (1.0f + erff(v * 0.70710678118654752f));
}
__device__ __forceinline__ f32x4 mfma16(s16x8 a, s16x8 b, f32x4 c) {
  return __builtin_amdgcn_mfma_f32_16x16x32_bf16(a, b, c, 0, 0, 0);
}
__device__ __forceinline__ void glds16(const u16* g, u16* l) {
  __builtin_amdgcn_global_load_lds(
      (const __attribute__((address_space(1))) unsigned int*)g,
      (__attribute__((address_space(3))) unsigned int*)l, 16, 0, 0);
}
// window (wi in [0,16), n in [0,512)) -> flat spatial token index
__device__ __forceinline__ int tok_of(int wi, int n) {
  int b = wi >> 3;
  int d = (((wi >> 2) & 1) << 3) | (n >> 6);
  int h = (((wi >> 1) & 1) << 3) | ((n >> 3) & 7);
  int w = ((wi & 1) << 3) | (n & 7);
  return (b << 12) | (d << 8) | (h << 4) | w;
}

// ---------------- weight fp32 -> bf16 ----------------
struct WConv {
  const float* src[8];
  u16* dst[8];
  int n[8];
};
__global__ __launch_bounds__(256) void conv_weights(WConv a) {
  int stride = gridDim.x * blockDim.x;
  int t0 = blockIdx.x * blockDim.x + threadIdx.x;
  for (int s = 0; s < 8; s++) {
    const float4* src = (const float4*)a.src[s];
    u16* dst = a.dst[s];
    int n4 = a.n[s] >> 2;
    for (int i = t0; i < n4; i += stride) {
      float4 v = src[i];
      ushort4 o;
      o.x = f2bf(v.x); o.y = f2bf(v.y); o.z = f2bf(v.z); o.w = f2bf(v.w);
      *(ushort4*)(dst + 4 * (size_t)i) = o;
    }
  }
}

// ---------------- LayerNorm (fp32 in -> bf16 out) ----------------
__global__ __launch_bounds__(256) void ln_bf16(const float* __restrict__ in,
    const float* __restrict__ gamma, const float* __restrict__ beta,
    u16* __restrict__ out) {
  const int row = blockIdx.x;
  const int tid = threadIdx.x;
  const float* xr = in + (size_t)row * NDIM;
  float v0 = xr[tid], v1 = xr[tid + 256], v2 = xr[tid + 512];
  float s = v0 + v1 + v2;
  float q = v0 * v0 + v1 * v1 + v2 * v2;
  for (int o = 32; o; o >>= 1) { s += __shfl_down(s, o); q += __shfl_down(q, o); }
  __shared__ float ss[4], sq[4];
  int wave = tid >> 6, lane = tid & 63;
  if (lane == 0) { ss[wave] = s; sq[wave] = q; }
  __syncthreads();
  s = ss[0] + ss[1] + ss[2] + ss[3];
  q = sq[0] + sq[1] + sq[2] + sq[3];
  float mean = s * (1.0f / 768.0f);
  float var = q * (1.0f / 768.0f) - mean * mean;
  float rstd = rsqrtf(var + 1e-5f);
  u16* orow = out + (size_t)row * NDIM;
  float v[3] = {v0, v1, v2};
  #pragma unroll
  for (int i = 0; i < 3; i++) {
    int c = tid + i * 256;
    orow[c] = f2bf((v[i] - mean) * rstd * gamma[c] + beta[c]);
  }
}

// ---------------- GEMM: C[M,N] = A[M,K](bf16) * W[N,K]^T(bf16) + bias ----------------
// EPI 0: bf16 store; 1: f32+bf16 store; 2: gelu->bf16; 3: h=add1+add2+v ->f32;
// EPI 4: out=add1+v ->f32; 5: out=add1+0.5v ->f32; 6: packed QKV store per window-head
template<int BM, int BN, int EPI>
__global__ __launch_bounds__(256) void gemm_bf16(
    const u16* __restrict__ A, const u16* __restrict__ W,
    const float* __restrict__ bias, int M, int N, int K,
    u16* __restrict__ obf, float* __restrict__ of,
    const float* __restrict__ add1, const float* __restrict__ add2) {
  constexpr int BK = 64;
  constexpr int WM = BM / 2, WN = BN / 2;
  constexpr int MF = WM / 16, NF = WN / 16;
  constexpr int ACH = BM * BK / (8 * 256);  // 16B chunks per thread for A
  constexpr int BCH = BN * BK / (8 * 256);
  __shared__ __align__(16) u16 As[BM * BK];
  __shared__ __align__(16) u16 Bs[BN * BK];
  const int bm = blockIdx.x, bn = blockIdx.y;
  const int tid = threadIdx.x;
  const int wave = tid >> 6, lane = tid & 63;
  const int wr = wave >> 1, wc = wave & 1;
  const int g = lane >> 4, c15 = lane & 15;
  f32x4 acc[MF][NF] = {};
  const u16* Ab = A + (size_t)(bm * BM) * K;
  const u16* Wb = W + (size_t)(bn * BN) * K;
  for (int k0 = 0; k0 < K; k0 += BK) {
    #pragma unroll
    for (int i = 0; i < ACH; i++) {
      int L = i * 256 + tid;           // 16B unit index; row = L>>3, unit = L&7
      glds16(Ab + (size_t)(L >> 3) * K + k0 + (L & 7) * 8, &As[L * 8]);
    }
    #pragma unroll
    for (int i = 0; i < BCH; i++) {
      int L = i * 256 + tid;
      glds16(Wb + (size_t)(L >> 3) * K + k0 + (L & 7) * 8, &Bs[L * 8]);
    }
    __syncthreads();
    #pragma unroll
    for (int h = 0; h < 2; h++) {
      s16x8 af[MF], bfr[NF];
      #pragma unroll
      for (int mi = 0; mi < MF; mi++)
        af[mi] = *(const s16x8*)&As[(wr * WM + mi * 16 + c15) * BK + h * 32 + g * 8];
      #pragma unroll
      for (int ni = 0; ni < NF; ni++)
        bfr[ni] = *(const s16x8*)&Bs[(wc * WN + ni * 16 + c15) * BK + h * 32 + g * 8];
      #pragma unroll
      for (int mi = 0; mi < MF; mi++)
        #pragma unroll
        for (int ni = 0; ni < NF; ni++)
          acc[mi][ni] = mfma16(af[mi], bfr[ni], acc[mi][ni]);
    }
    __syncthreads();
  }
  #pragma unroll
  for (int mi = 0; mi < MF; mi++) {
    #pragma unroll
    for (int ni = 0; ni < NF; ni++) {
      int col = bn * BN + wc * WN + ni * 16 + c15;
      float bv = bias[col];
      #pragma unroll
      for (int j = 0; j < 4; j++) {
        int row = bm * BM + wr * WM + mi * 16 + g * 4 + j;
        size_t idx = (size_t)row * N + col;
        float v = acc[mi][ni][j] + bv;
        if (EPI == 0) {
          obf[idx] = f2bf(v);
        } else if (EPI == 1) {
          of[idx] = v; obf[idx] = f2bf(v);
        } else if (EPI == 2) {
          obf[idx] = f2bf(gelu_f(v));
        } else if (EPI == 3) {
          of[idx] = add1[idx] + add2[idx] + v;
        } else if (EPI == 4) {
          of[idx] = add1[idx] + v;
        } else if (EPI == 5) {
          of[idx] = add1[idx] + 0.5f * v;
        } else if (EPI == 6) {
          // packed QKV: seg 0/1/2 -> Qp/Kp/Vp [whi][n][64]
          int seg = col >= 1536 ? 2 : (col >= 768 ? 1 : 0);
          int cc_ = col - seg * 768;
          int hh = cc_ >> 6, c = cc_ & 63;
          int t = row;
          int b = t >> 12, d = (t >> 8) & 15, hy = (t >> 4) & 15, wx = t & 15;
          int wi = (b << 3) | ((d >> 3) << 2) | ((hy >> 3) << 1) | (wx >> 3);
          int n = ((d & 7) << 6) | ((hy & 7) << 3) | (wx & 7);
          obf[(size_t)seg * (WHN * WHSZ) +
              ((size_t)(wi * NHEADS + hh) * 512 + n) * 64 + c] = f2bf(v);
        }
      }
    }
  }
}

// ---------------- transpose Vp[whi][n][c] -> Vt[whi][c][n] ----------------
__global__ __launch_bounds__(256) void repack_v(const u16* __restrict__ vp,
                                                u16* __restrict__ vt) {
  int whi = blockIdx.x;
  __shared__ u16 Vs[512 * 64];  // XOR-swizzled: slot(n,c) = n*64 + (c ^ (n&63))
  int tid = threadIdx.x;
  const u16* src = vp + (size_t)whi * WHSZ;
  for (int idx = tid; idx < 512 * 64; idx += 256) {
    int n = idx >> 6, c = idx & 63;
    Vs[(n << 6) | (c ^ (n & 63))] = src[idx];
  }
  __syncthreads();
  size_t base = (size_t)whi * WHSZ;
  #pragma unroll 1
  for (int i = 0; i < 32; i++) {
    int idx4 = tid + i * 256;  // 0..8191
    int c = idx4 >> 7, np = (idx4 & 127) << 2;
    ushort4 o;
    o.x = Vs[((np + 0) << 6) | (c ^ ((np + 0) & 63))];
    o.y = Vs[((np + 1) << 6) | (c ^ ((np + 1) & 63))];
    o.z = Vs[((np + 2) << 6) | (c ^ ((np + 2) & 63))];
    o.w = Vs[((np + 3) << 6) | (c ^ ((np + 3) & 63))];
    *(ushort4*)(vt + base + (size_t)c * 512 + np) = o;
  }
}

// ---------------- windowed attention: LDS-staged K/V, deferred block-max softmax ----
// grid: 1536 blocks, blk = qblk*192 + whi (same whi -> same XCD L2)
// 4 waves x 16 q-rows; 64-key chunks; per-16-row block max (exact for softmax);
// one 4-step shfl chain per chunk; l-sum deferred to epilogue.
__global__ __launch_bounds__(256) void attn_win(const u16* __restrict__ Qp,
    const u16* __restrict__ Kp, const u16* __restrict__ vt,
    const float* __restrict__ rpd, const float* __restrict__ rph,
    const float* __restrict__ rpw, u16* __restrict__ out) {
  int blk = blockIdx.x;
  int whi = blk % WHN, qblk = blk / WHN;
  int wi = whi / NHEADS, hh = whi % NHEADS;
  int tid = threadIdx.x;
  int wave = tid >> 6, lane = tid & 63;
  int g = lane >> 4, c15 = lane & 15;
  int n0 = qblk * 64 + wave * 16;
  __shared__ __align__(16) u16 Ks[2][4096];    // 64 rows x 64 u16, 16B-unit XOR-swizzled
  __shared__ __align__(16) u16 Vs[2][4096];    // 64 c-rows x 64 keys, same swizzle
  __shared__ float rel_s[4][3][16][8];
  __shared__ __align__(16) u16 p_lds[4][16][72];  // row stride 144B
  const u16* qbase = Qp + (size_t)whi * WHSZ;
  const u16* kbase = Kp + (size_t)whi * WHSZ;
  const u16* vbase = vt + (size_t)whi * WHSZ;

  // stage one 64-key chunk of K and V into LDS buffer `buf`
  // row r (0..63), 8 units of 16B; unit u stored at slot (u ^ (r&7))
  // via pre-swizzled per-lane GLOBAL source address (dest stays linear)
  auto stage = [&](int kc, int buf) {
    #pragma unroll
    for (int i = 0; i < 2; i++) {
      int seg = wave * 2048 + i * 1024 + lane * 16;  // byte offset in 8KB buffer
      int r = seg >> 7, u = (seg >> 4) & 7;
      int su = (u ^ (r & 7)) << 3;                   // swizzled unit, u16 offset
      glds16(kbase + (size_t)(kc + r) * 64 + su, &Ks[buf][seg >> 1]);
      glds16(vbase + (size_t)r * 512 + kc + su, &Vs[buf][seg >> 1]);
    }
  };

  stage(0, 0);  // chunk 0 -> buf 0 (latency overlaps prolog below)

  // Q A-fragments (rows n0..n0+15, k split 0..31 / 32..63)
  const u16* qb = qbase + (size_t)(n0 + c15) * 64;
  s16x8 a0 = *(const s16x8*)(qb + g * 8);
  s16x8 a1 = *(const s16x8*)(qb + 32 + g * 8);
  // rel-pos tables: rel_s[w][axis][r][kx] = dot(q[n0+r], rel_pos_axis[coord-kx+7])
  for (int e = lane; e < 384; e += 64) {
    int ti = e >> 7, rr = (e >> 3) & 15, kx = e & 7;
    int n = n0 + rr;
    int coord = (ti == 0) ? (n >> 6) : (ti == 1) ? ((n >> 3) & 7) : (n & 7);
    const float* rp = ((ti == 0) ? rpd : (ti == 1) ? rph : rpw) + (coord - kx + 7) * 64;
    const u16* qr = qbase + (size_t)n * 64;
    float s = 0.f;
    for (int cb = 0; cb < 64; cb += 8) {
      s16x8 qv = *(const s16x8*)(qr + cb);
      const float4* rp4 = (const float4*)(rp + cb);
      float4 rA = rp4[0], rB = rp4[1];
      s += bf2f((u16)qv[0]) * rA.x + bf2f((u16)qv[1]) * rA.y +
           bf2f((u16)qv[2]) * rA.z + bf2f((u16)qv[3]) * rA.w +
           bf2f((u16)qv[4]) * rB.x + bf2f((u16)qv[5]) * rB.y +
           bf2f((u16)qv[6]) * rB.z + bf2f((u16)qv[7]) * rB.w;
    }
    rel_s[wave][ti][rr][kx] = s;
  }
  __syncthreads();  // chunk0 staged + rel_s ready

  // hoist rel_h/rel_w into registers:
  // kw = c15&7 (lane-const); kh = (cc*2 + (c15>>3)) & 7 (kc-independent)
  float rbias[4][4];  // [cc][j] = rel_h + rel_w
  #pragma unroll
  for (int j = 0; j < 4; j++) {
    float rw_ = rel_s[wave][2][g * 4 + j][c15 & 7];
    #pragma unroll
    for (int cc = 0; cc < 4; cc++)
      rbias[cc][j] = rel_s[wave][1][g * 4 + j][(cc * 2 + (c15 >> 3)) & 7] + rw_;
  }

  float m_ = -1e30f;                     // per-16-row block max (uniform in 16-lane grp)
  float l_[4] = {0.f, 0.f, 0.f, 0.f};   // per-lane partial denominators
  f32x4 o_[4] = {};

  for (int c = 0; c < 8; c++) {
    int buf = c & 1;
    int kc = c * 64;
    if (c < 7) stage(kc + 64, buf ^ 1);  // prefetch next chunk (drains at barrier)
    // ---- QK^T: 64 keys, S in registers ----
    f32x4 s[4];
    #pragma unroll
    for (int cc = 0; cc < 4; cc++) {
      int r = cc * 16 + c15;
      const u16* kr = &Ks[buf][r * 64];
      s16x8 k0 = *(const s16x8*)(kr + ((g ^ (r & 7)) << 3));
      s16x8 k1 = *(const s16x8*)(kr + (((4 + g) ^ (r & 7)) << 3));
      f32x4 t = {0.f, 0.f, 0.f, 0.f};
      t = mfma16(a0, k0, t);
      s[cc] = mfma16(a1, k1, t);
    }
    // ---- scale + rel-pos (rel_d uniform per chunk; rest in registers) ----
    float rdv[4];
    #pragma unroll
    for (int j = 0; j < 4; j++) rdv[j] = rel_s[wave][0][g * 4 + j][kc >> 6];
    #pragma unroll
    for (int cc = 0; cc < 4; cc++)
      #pragma unroll
      for (int j = 0; j < 4; j++)
        s[cc][j] = s[cc][j] * QK_SCALE + (rdv[j] + rbias[cc][j]);
    // ---- deferred block-max online softmax ----
    float mx = fmaxf(fmaxf(fmaxf(s[0][0], s[0][1]), fmaxf(s[0][2], s[0][3])),
                     fmaxf(fmaxf(s[1][0], s[1][1]), fmaxf(s[1][2], s[1][3])));
    mx = fmaxf(mx, fmaxf(fmaxf(fmaxf(s[2][0], s[2][1]), fmaxf(s[2][2], s[2][3])),
                         fmaxf(fmaxf(s[3][0], s[3][1]), fmaxf(s[3][2], s[3][3]))));
    #pragma unroll
    for (int msk = 1; msk < 16; msk <<= 1) mx = fmaxf(mx, __shfl_xor(mx, msk));
    if (__any(mx > m_ + 8.f)) {          // rare after chunk 0 (defer-max, THR=8)
      float mn = fmaxf(m_, mx);
      float corr = __expf(m_ - mn);
      #pragma unroll
      for (int j = 0; j < 4; j++) l_[j] *= corr;
      #pragma unroll
      for (int cf = 0; cf < 4; cf++)
        #pragma unroll
        for (int j = 0; j < 4; j++) o_[cf][j] *= corr;
      m_ = mn;
    }
    #pragma unroll
    for (int cc = 0; cc < 4; cc++) {
      #pragma unroll
      for (int j = 0; j < 4; j++) {
        float p = __expf(s[cc][j] - m_);
        l_[j] += p;
        p_lds[wave][g * 4 + j][cc * 16 + c15] = f2bf(p);
      }
    }
    // wave-private P handoff (rule #18 fence)
    asm volatile("s_waitcnt lgkmcnt(0)" ::: "memory");
    __builtin_amdgcn_sched_barrier(0);
    // ---- PV: P (16x64) x V^T (64x64) ----
    s16x8 pa0 = *(const s16x8*)&p_lds[wave][c15][g * 8];
    s16x8 pa1 = *(const s16x8*)&p_lds[wave][c15][32 + g * 8];
    #pragma unroll
    for (int cf = 0; cf < 4; cf++) {
      int cv = cf * 16 + c15;
      const u16* vr = &Vs[buf][cv * 64];
      o_[cf] = mfma16(pa0, *(const s16x8*)(vr + ((g ^ (cv & 7)) << 3)), o_[cf]);
      o_[cf] = mfma16(pa1, *(const s16x8*)(vr + (((4 + g) ^ (cv & 7)) << 3)), o_[cf]);
    }
    __syncthreads();  // next chunk staged; all waves done with buf
  }
  // epilogue: reduce row denominators across the 16 key-lanes, then normalize
  #pragma unroll
  for (int j = 0; j < 4; j++) {
    #pragma unroll
    for (int msk = 1; msk < 16; msk <<= 1) l_[j] += __shfl_xor(l_[j], msk);
    l_[j] = 1.0f / l_[j];
  }
  #pragma unroll
  for (int j = 0; j < 4; j++) {
    int t = tok_of(wi, n0 + g * 4 + j);
    u16* orow = out + (size_t)t * NDIM + hh * 64;
    #pragma unroll
    for (int cf = 0; cf < 4; cf++) orow[cf * 16 + c15] = f2bf(o_[cf][j] * l_[j]);
  }
}

extern "C" void kernel_launch(void* const* d_in, const int* in_sizes, int n_in,
                              void* d_out, int out_size, void* d_ws, size_t ws_size,
                              hipStream_t stream) {
  const float* x     = (const float*)d_in[0];
  const float* ln1_g = (const float*)d_in[1];
  const float* ln1_b = (const float*)d_in[2];
  const float* qkv_w = (const float*)d_in[3];
  const float* qkv_b = (const float*)d_in[4];
  const float* rpd   = (const float*)d_in[5];
  const float* rph   = (const float*)d_in[6];
  const float* rpw   = (const float*)d_in[7];
  const float* proj_w = (const float*)d_in[8];
  const float* proj_b = (const float*)d_in[9];
  const float* aa1_w = (const float*)d_in[10];
  const float* aa1_b = (const float*)d_in[11];
  const float* aa2_w = (const float*)d_in[12];
  const float* aa2_b = (const float*)d_in[13];
  const float* ln2_g = (const float*)d_in[14];
  const float* ln2_b = (const float*)d_in[15];
  const float* mlp1_w = (const float*)d_in[16];
  const float* mlp1_b = (const float*)d_in[17];
  const float* mlp2_w = (const float*)d_in[18];
  const float* mlp2_b = (const float*)d_in[19];
  const float* ma1_w = (const float*)d_in[20];
  const float* ma1_b = (const float*)d_in[21];
  const float* ma2_w = (const float*)d_in[22];
  const float* ma2_b = (const float*)d_in[23];
  float* out = (float*)d_out;
  char* ws = (char*)d_ws;

  // arena (explicit lifetimes; total ~157 MB)
  u16* wqkv  = (u16*)(ws + 0);          // 3538944 B
  u16* wproj = (u16*)(ws + 3538944);    // 1179648
  u16* wmlp1 = (u16*)(ws + 4718592);    // 4718592
  u16* wmlp2 = (u16*)(ws + 9437184);    // 4718592
  u16* waa1  = (u16*)(ws + 14155776);   // 294912
  u16* waa2  = (u16*)(ws + 14450688);   // 294912
  u16* wma1  = (u16*)(ws + 14745600);   // 294912
  u16* wma2  = (u16*)(ws + 15040512);   // 294912
  u16* h1    = (u16*)(ws + 15335424);   // 12.58 MB: LN1 out, then reused as attn_out
  u16* attno = h1;
  u16* qkvp  = (u16*)(ws + 27918336);   // 37.75 MB: packed Qp|Kp|Vp, then p_f32 + p_bf16
  float* p_f = (float*)(ws + 27918336);
  u16* p_bf  = (u16*)(ws + 53084160);
  u16* vtp   = (u16*)(ws + 65667072);   // 12.58 MB: V_t, then hn
  u16* hn    = vtp;
  float* h_f = (float*)(ws + 78249984); // 25.17 MB
  u16* ah    = (u16*)(ws + 103415808);  // adapter hidden, then mlp hidden (50.33 MB)
  u16* mlph  = ah;
  u16* mah   = (u16*)(ws + 153747456);  // 3.15 MB
  (void)ws_size; (void)in_sizes; (void)n_in; (void)out_size;

  u16* Qp = qkvp;
  u16* Kp = qkvp + (size_t)WHN * WHSZ;
  u16* Vp = qkvp + 2 * (size_t)WHN * WHSZ;

  WConv wc;
  wc.src[0] = qkv_w;  wc.dst[0] = wqkv;  wc.n[0] = 2304 * 768;
  wc.src[1] = proj_w; wc.dst[1] = wproj; wc.n[1] = 768 * 768;
  wc.src[2] = mlp1_w; wc.dst[2] = wmlp1; wc.n[2] = 3072 * 768;
  wc.src[3] = mlp2_w; wc.dst[3] = wmlp2; wc.n[3] = 768 * 3072;
  wc.src[4] = aa1_w;  wc.dst[4] = waa1;  wc.n[4] = 192 * 768;
  wc.src[5] = aa2_w;  wc.dst[5] = waa2;  wc.n[5] = 768 * 192;
  wc.src[6] = ma1_w;  wc.dst[6] = wma1;  wc.n[6] = 192 * 768;
  wc.src[7] = ma2_w;  wc.dst[7] = wma2;  wc.n[7] = 768 * 192;
  conv_weights<<<1024, 256, 0, stream>>>(wc);

  ln_bf16<<<TOK, 256, 0, stream>>>(x, ln1_g, ln1_b, h1);
  gemm_bf16<128, 128, 6><<<dim3(64, 18), 256, 0, stream>>>(h1, wqkv, qkv_b, TOK, 2304, 768,
                                                           qkvp, nullptr, nullptr, nullptr);
  repack_v<<<192, 256, 0, stream>>>(Vp, vtp);
  attn_win<<<1536, 256, 0, stream>>>(Qp, Kp, vtp, rpd, rph, rpw, attno);
  gemm_bf16<128, 64, 1><<<dim3(64, 12), 256, 0, stream>>>(attno, wproj, proj_b, TOK, 768, 768,
                                                          p_bf, p_f, nullptr, nullptr);
  gemm_bf16<64, 64, 2><<<dim3(128, 3), 256, 0, stream>>>(p_bf, waa1, aa1_b, TOK, 192, 768,
                                                         ah, nullptr, nullptr, nullptr);
  gemm_bf16<128, 64, 3><<<dim3(64, 12), 256, 0, stream>>>(ah, waa2, aa2_b, TOK, 768, 192,
                                                          nullptr, h_f, x, p_f);
  ln_bf16<<<TOK, 256, 0, stream>>>(h_f, ln2_g, ln2_b, hn);
  gemm_bf16<128, 128, 2><<<dim3(64, 24), 256, 0, stream>>>(hn, wmlp1, mlp1_b, TOK, 3072, 768,
                                                           mlph, nullptr, nullptr, nullptr);
  gemm_bf16<128, 64, 4><<<dim3(64, 12), 256, 0, stream>>>(mlph, wmlp2, mlp2_b, TOK, 768, 3072,
                                                          nullptr, out, h_f, nullptr);
  gemm_bf16<64, 64, 2><<<dim3(128, 3), 256, 0, stream>>>(hn, wma1, ma1_b, TOK, 192, 768,
                                                         mah, nullptr, nullptr, nullptr);
  gemm_bf16<128, 64, 5><<<dim3(64, 12), 256, 0, stream>>>(mah, wma2, ma2_b, TOK, 768, 192,
                                                          nullptr, out, out, nullptr);
}

// Round 6
// 384.014 us; speedup vs baseline: 1.3468x; 1.1676x over previous
//
#include <hip/hip_runtime.h>

typedef unsigned short u16;
typedef __attribute__((ext_vector_type(4))) float f32x4;
typedef __attribute__((ext_vector_type(8))) short s16x8;

#define TOK 8192
#define NDIM 768
#define NHEADS 12
#define QK_SCALE 0.125f
#define WHN 192            // window-heads
#define WHSZ 32768         // 512*64 elements per window-head plane

__device__ __forceinline__ u16 f2bf(float f) {
  union { float f; unsigned u; } x; x.f = f;
  unsigned r = x.u + 0x7fffu + ((x.u >> 16) & 1u);
  return (u16)(r >> 16);
}
__device__ __forceinline__ float bf2f(u16 u) {
  union { unsigned u; float f; } x; x.u = ((unsigned)u) << 16;
  return x.f;
}
__device__ __forceinline__ float gelu_f(float v) {
  return 0.5f * v * (1.0f + erff(v * 0.70710678118654752f));
}
__device__ __forceinline__ f32x4 mfma16(s16x8 a, s16x8 b, f32x4 c) {
  return __builtin_amdgcn_mfma_f32_16x16x32_bf16(a, b, c, 0, 0, 0);
}
__device__ __forceinline__ void glds16(const u16* g, u16* l) {
  __builtin_amdgcn_global_load_lds(
      (const __attribute__((address_space(1))) unsigned int*)g,
      (__attribute__((address_space(3))) unsigned int*)l, 16, 0, 0);
}
// window (wi in [0,16), n in [0,512)) -> flat spatial token index
__device__ __forceinline__ int tok_of(int wi, int n) {
  int b = wi >> 3;
  int d = (((wi >> 2) & 1) << 3) | (n >> 6);
  int h = (((wi >> 1) & 1) << 3) | ((n >> 3) & 7);
  int w = ((wi & 1) << 3) | (n & 7);
  return (b << 12) | (d << 8) | (h << 4) | w;
}

// ---------------- weight fp32 -> bf16 ----------------
struct WConv {
  const float* src[8];
  u16* dst[8];
  int n[8];
};
__global__ __launch_bounds__(256) void conv_weights(WConv a) {
  int stride = gridDim.x * blockDim.x;
  int t0 = blockIdx.x * blockDim.x + threadIdx.x;
  for (int s = 0; s < 8; s++) {
    const float4* src = (const float4*)a.src[s];
    u16* dst = a.dst[s];
    int n4 = a.n[s] >> 2;
    for (int i = t0; i < n4; i += stride) {
      float4 v = src[i];
      ushort4 o;
      o.x = f2bf(v.x); o.y = f2bf(v.y); o.z = f2bf(v.z); o.w = f2bf(v.w);
      *(ushort4*)(dst + 4 * (size_t)i) = o;
    }
  }
}

// ---------------- LayerNorm (fp32 in -> bf16 out) ----------------
__global__ __launch_bounds__(256) void ln_bf16(const float* __restrict__ in,
    const float* __restrict__ gamma, const float* __restrict__ beta,
    u16* __restrict__ out) {
  const int row = blockIdx.x;
  const int tid = threadIdx.x;
  const float* xr = in + (size_t)row * NDIM;
  float v0 = xr[tid], v1 = xr[tid + 256], v2 = xr[tid + 512];
  float s = v0 + v1 + v2;
  float q = v0 * v0 + v1 * v1 + v2 * v2;
  for (int o = 32; o; o >>= 1) { s += __shfl_down(s, o); q += __shfl_down(q, o); }
  __shared__ float ss[4], sq[4];
  int wave = tid >> 6, lane = tid & 63;
  if (lane == 0) { ss[wave] = s; sq[wave] = q; }
  __syncthreads();
  s = ss[0] + ss[1] + ss[2] + ss[3];
  q = sq[0] + sq[1] + sq[2] + sq[3];
  float mean = s * (1.0f / 768.0f);
  float var = q * (1.0f / 768.0f) - mean * mean;
  float rstd = rsqrtf(var + 1e-5f);
  u16* orow = out + (size_t)row * NDIM;
  float v[3] = {v0, v1, v2};
  #pragma unroll
  for (int i = 0; i < 3; i++) {
    int c = tid + i * 256;
    orow[c] = f2bf((v[i] - mean) * rstd * gamma[c] + beta[c]);
  }
}

// ---- GEMM: C[M,N] = A[M,K](bf16) * W[N,K]^T(bf16) + bias; dbuf prefetch pipeline ----
// EPI 0: bf16 store; 1: f32+bf16 store; 2: gelu->bf16; 3: h=add1+add2+v ->f32;
// EPI 4: out=add1+v ->f32; 5: out=add1+0.5v ->f32; 6: packed QKV store per window-head
template<int BM, int BN, int EPI>
__global__ __launch_bounds__(256) void gemm_bf16(
    const u16* __restrict__ A, const u16* __restrict__ W,
    const float* __restrict__ bias, int M, int N, int K,
    u16* __restrict__ obf, float* __restrict__ of,
    const float* __restrict__ add1, const float* __restrict__ add2) {
  constexpr int BK = 32;
  constexpr int WM = BM / 2, WN = BN / 2;
  constexpr int MF = WM / 16, NF = WN / 16;
  constexpr int ACH = BM * BK / (8 * 256);  // 16B chunks per thread for A
  constexpr int BCH = BN * BK / (8 * 256);
  __shared__ __align__(16) u16 As[2][BM * BK];
  __shared__ __align__(16) u16 Bs[2][BN * BK];
  const int bm = blockIdx.x, bn = blockIdx.y;
  const int tid = threadIdx.x;
  const int wave = tid >> 6, lane = tid & 63;
  const int wr = wave >> 1, wc = wave & 1;
  const int g = lane >> 4, c15 = lane & 15;
  f32x4 acc[MF][NF] = {};
  const u16* Ab = A + (size_t)(bm * BM) * K;
  const u16* Wb = W + (size_t)(bn * BN) * K;
  // stage: linear LDS dest, XOR-swizzled global source (unit u -> u ^ (row&3))
  auto stage = [&](int k0, int b) {
    #pragma unroll
    for (int i = 0; i < ACH; i++) {
      int L = i * 256 + tid;  // row = L>>2, unit = L&3
      glds16(Ab + (size_t)(L >> 2) * K + k0 + (((L & 3) ^ ((L >> 2) & 3)) * 8),
             &As[b][L * 8]);
    }
    #pragma unroll
    for (int i = 0; i < BCH; i++) {
      int L = i * 256 + tid;
      glds16(Wb + (size_t)(L >> 2) * K + k0 + (((L & 3) ^ ((L >> 2) & 3)) * 8),
             &Bs[b][L * 8]);
    }
  };
  stage(0, 0);
  __syncthreads();
  const int NT = K / BK;
  for (int t = 0; t < NT; t++) {
    int buf = t & 1;
    if (t + 1 < NT) stage((t + 1) * BK, buf ^ 1);  // prefetch overlaps compute
    s16x8 af[MF], bfr[NF];
    #pragma unroll
    for (int mi = 0; mi < MF; mi++) {
      int r = wr * WM + mi * 16 + c15;
      af[mi] = *(const s16x8*)&As[buf][r * BK + ((g ^ (r & 3)) << 3)];
    }
    #pragma unroll
    for (int ni = 0; ni < NF; ni++) {
      int r = wc * WN + ni * 16 + c15;
      bfr[ni] = *(const s16x8*)&Bs[buf][r * BK + ((g ^ (r & 3)) << 3)];
    }
    #pragma unroll
    for (int mi = 0; mi < MF; mi++)
      #pragma unroll
      for (int ni = 0; ni < NF; ni++)
        acc[mi][ni] = mfma16(af[mi], bfr[ni], acc[mi][ni]);
    __syncthreads();  // drains prefetch (vmcnt0); all waves done with buf
  }
  #pragma unroll
  for (int mi = 0; mi < MF; mi++) {
    #pragma unroll
    for (int ni = 0; ni < NF; ni++) {
      int col = bn * BN + wc * WN + ni * 16 + c15;
      float bv = bias[col];
      #pragma unroll
      for (int j = 0; j < 4; j++) {
        int row = bm * BM + wr * WM + mi * 16 + g * 4 + j;
        size_t idx = (size_t)row * N + col;
        float v = acc[mi][ni][j] + bv;
        if (EPI == 0) {
          obf[idx] = f2bf(v);
        } else if (EPI == 1) {
          of[idx] = v; obf[idx] = f2bf(v);
        } else if (EPI == 2) {
          obf[idx] = f2bf(gelu_f(v));
        } else if (EPI == 3) {
          of[idx] = add1[idx] + add2[idx] + v;
        } else if (EPI == 4) {
          of[idx] = add1[idx] + v;
        } else if (EPI == 5) {
          of[idx] = add1[idx] + 0.5f * v;
        } else if (EPI == 6) {
          // packed QKV: seg 0/1/2 -> Qp/Kp/Vp [whi][n][64]
          int seg = col >= 1536 ? 2 : (col >= 768 ? 1 : 0);
          int cc_ = col - seg * 768;
          int hh = cc_ >> 6, c = cc_ & 63;
          int t = row;
          int b = t >> 12, d = (t >> 8) & 15, hy = (t >> 4) & 15, wx = t & 15;
          int wi = (b << 3) | ((d >> 3) << 2) | ((hy >> 3) << 1) | (wx >> 3);
          int n = ((d & 7) << 6) | ((hy & 7) << 3) | (wx & 7);
          obf[(size_t)seg * (WHN * WHSZ) +
              ((size_t)(wi * NHEADS + hh) * 512 + n) * 64 + c] = f2bf(v);
        }
      }
    }
  }
}

// ---------------- transpose Vp[whi][n][c] -> Vt[whi][c][n] ----------------
__global__ __launch_bounds__(256) void repack_v(const u16* __restrict__ vp,
                                                u16* __restrict__ vt) {
  int whi = blockIdx.x;
  __shared__ u16 Vs[512 * 64];  // XOR-swizzled: slot(n,c) = n*64 + (c ^ (n&63))
  int tid = threadIdx.x;
  const u16* src = vp + (size_t)whi * WHSZ;
  for (int idx = tid; idx < 512 * 64; idx += 256) {
    int n = idx >> 6, c = idx & 63;
    Vs[(n << 6) | (c ^ (n & 63))] = src[idx];
  }
  __syncthreads();
  size_t base = (size_t)whi * WHSZ;
  #pragma unroll 1
  for (int i = 0; i < 32; i++) {
    int idx4 = tid + i * 256;  // 0..8191
    int c = idx4 >> 7, np = (idx4 & 127) << 2;
    ushort4 o;
    o.x = Vs[((np + 0) << 6) | (c ^ ((np + 0) & 63))];
    o.y = Vs[((np + 1) << 6) | (c ^ ((np + 1) & 63))];
    o.z = Vs[((np + 2) << 6) | (c ^ ((np + 2) & 63))];
    o.w = Vs[((np + 3) << 6) | (c ^ ((np + 3) & 63))];
    *(ushort4*)(vt + base + (size_t)c * 512 + np) = o;
  }
}

// ------- windowed attention: 2 Q-tiles/wave, LDS-staged K/V, deferred block-max -----
// grid: 768 blocks, blk = qblk*192 + whi (same whi -> same XCD L2)
// 4 waves x 32 q-rows (2 tiles of 16); 64-key chunks; K frag reused across tiles
__global__ __launch_bounds__(256) void attn_win(const u16* __restrict__ Qp,
    const u16* __restrict__ Kp, const u16* __restrict__ vt,
    const float* __restrict__ rpd, const float* __restrict__ rph,
    const float* __restrict__ rpw, u16* __restrict__ out) {
  int blk = blockIdx.x;
  int whi = blk % WHN, qblk = blk / WHN;
  int wi = whi / NHEADS, hh = whi % NHEADS;
  int tid = threadIdx.x;
  int wave = tid >> 6, lane = tid & 63;
  int g = lane >> 4, c15 = lane & 15;
  int n0 = qblk * 128 + wave * 32;
  __shared__ __align__(16) u16 Ks[2][4096];    // 64 rows x 64 u16, 16B-unit XOR-swizzled
  __shared__ __align__(16) u16 Vs[2][4096];    // 64 c-rows x 64 keys, same swizzle
  __shared__ float rel_s[4][3][32][8];
  __shared__ __align__(16) u16 p_lds[4][16][72];  // one tile at a time, stride 144B
  const u16* qbase = Qp + (size_t)whi * WHSZ;
  const u16* kbase = Kp + (size_t)whi * WHSZ;
  const u16* vbase = vt + (size_t)whi * WHSZ;

  auto stage = [&](int kc, int buf) {
    #pragma unroll
    for (int i = 0; i < 2; i++) {
      int seg = wave * 2048 + i * 1024 + lane * 16;  // byte offset in 8KB buffer
      int r = seg >> 7, u = (seg >> 4) & 7;
      int su = (u ^ (r & 7)) << 3;                   // swizzled unit, u16 offset
      glds16(kbase + (size_t)(kc + r) * 64 + su, &Ks[buf][seg >> 1]);
      glds16(vbase + (size_t)r * 512 + kc + su, &Vs[buf][seg >> 1]);
    }
  };

  stage(0, 0);  // chunk 0 -> buf 0 (latency overlaps prolog below)

  // Q A-fragments for the two 16-row tiles
  const u16* qbA = qbase + (size_t)(n0 + c15) * 64;
  const u16* qbB = qbase + (size_t)(n0 + 16 + c15) * 64;
  s16x8 aA0 = *(const s16x8*)(qbA + g * 8);
  s16x8 aA1 = *(const s16x8*)(qbA + 32 + g * 8);
  s16x8 aB0 = *(const s16x8*)(qbB + g * 8);
  s16x8 aB1 = *(const s16x8*)(qbB + 32 + g * 8);
  // rel-pos tables for 32 rows: rel_s[w][axis][r][kx]
  for (int e = lane; e < 768; e += 64) {
    int ti = e >> 8, rr = (e >> 3) & 31, kx = e & 7;
    int n = n0 + rr;
    int coord = (ti == 0) ? (n >> 6) : (ti == 1) ? ((n >> 3) & 7) : (n & 7);
    const float* rp = ((ti == 0) ? rpd : (ti == 1) ? rph : rpw) + (coord - kx + 7) * 64;
    const u16* qr = qbase + (size_t)n * 64;
    float s = 0.f;
    for (int cb = 0; cb < 64; cb += 8) {
      s16x8 qv = *(const s16x8*)(qr + cb);
      const float4* rp4 = (const float4*)(rp + cb);
      float4 rA = rp4[0], rB = rp4[1];
      s += bf2f((u16)qv[0]) * rA.x + bf2f((u16)qv[1]) * rA.y +
           bf2f((u16)qv[2]) * rA.z + bf2f((u16)qv[3]) * rA.w +
           bf2f((u16)qv[4]) * rB.x + bf2f((u16)qv[5]) * rB.y +
           bf2f((u16)qv[6]) * rB.z + bf2f((u16)qv[7]) * rB.w;
    }
    rel_s[wave][ti][rr][kx] = s;
  }
  __syncthreads();  // chunk0 staged + rel_s ready

  // hoist rel_h + rel_w into registers (kw = c15&7; kh = (cc*2+(c15>>3))&7)
  float rbA[4][4], rbB[4][4];
  #pragma unroll
  for (int j = 0; j < 4; j++) {
    float rwA = rel_s[wave][2][g * 4 + j][c15 & 7];
    float rwB = rel_s[wave][2][16 + g * 4 + j][c15 & 7];
    #pragma unroll
    for (int cc = 0; cc < 4; cc++) {
      int kh = (cc * 2 + (c15 >> 3)) & 7;
      rbA[cc][j] = rel_s[wave][1][g * 4 + j][kh] + rwA;
      rbB[cc][j] = rel_s[wave][1][16 + g * 4 + j][kh] + rwB;
    }
  }

  float mA = -1e30f, mB = -1e30f;
  float lA[4] = {0.f, 0.f, 0.f, 0.f}, lB[4] = {0.f, 0.f, 0.f, 0.f};
  f32x4 oA[4] = {}, oB[4] = {};

  for (int c = 0; c < 8; c++) {
    int buf = c & 1;
    if (c < 7) stage(c * 64 + 64, buf ^ 1);  // prefetch next chunk
    // ---- QK^T both tiles, K fragments loaded once ----
    f32x4 sA[4], sB[4];
    #pragma unroll
    for (int cc = 0; cc < 4; cc++) {
      int r = cc * 16 + c15;
      const u16* kr = &Ks[buf][r * 64];
      s16x8 k0 = *(const s16x8*)(kr + ((g ^ (r & 7)) << 3));
      s16x8 k1 = *(const s16x8*)(kr + (((4 + g) ^ (r & 7)) << 3));
      f32x4 t0 = {0.f, 0.f, 0.f, 0.f};
      t0 = mfma16(aA0, k0, t0);
      sA[cc] = mfma16(aA1, k1, t0);
      f32x4 t1 = {0.f, 0.f, 0.f, 0.f};
      t1 = mfma16(aB0, k0, t1);
      sB[cc] = mfma16(aB1, k1, t1);
    }
    // ---- scale + rel-pos ----
    float rdA[4], rdB[4];
    #pragma unroll
    for (int j = 0; j < 4; j++) {
      rdA[j] = rel_s[wave][0][g * 4 + j][c];
      rdB[j] = rel_s[wave][0][16 + g * 4 + j][c];
    }
    #pragma unroll
    for (int cc = 0; cc < 4; cc++)
      #pragma unroll
      for (int j = 0; j < 4; j++) {
        sA[cc][j] = sA[cc][j] * QK_SCALE + (rdA[j] + rbA[cc][j]);
        sB[cc][j] = sB[cc][j] * QK_SCALE + (rdB[j] + rbB[cc][j]);
      }
    // ================= tile A: softmax + PV =================
    {
      float mx = fmaxf(fmaxf(fmaxf(sA[0][0], sA[0][1]), fmaxf(sA[0][2], sA[0][3])),
                       fmaxf(fmaxf(sA[1][0], sA[1][1]), fmaxf(sA[1][2], sA[1][3])));
      mx = fmaxf(mx, fmaxf(fmaxf(fmaxf(sA[2][0], sA[2][1]), fmaxf(sA[2][2], sA[2][3])),
                           fmaxf(fmaxf(sA[3][0], sA[3][1]), fmaxf(sA[3][2], sA[3][3]))));
      #pragma unroll
      for (int msk = 1; msk < 16; msk <<= 1) mx = fmaxf(mx, __shfl_xor(mx, msk));
      if (__any(mx > mA + 8.f)) {
        float mn = fmaxf(mA, mx);
        float corr = __expf(mA - mn);
        #pragma unroll
        for (int j = 0; j < 4; j++) lA[j] *= corr;
        #pragma unroll
        for (int cf = 0; cf < 4; cf++)
          #pragma unroll
          for (int j = 0; j < 4; j++) oA[cf][j] *= corr;
        mA = mn;
      }
      #pragma unroll
      for (int cc = 0; cc < 4; cc++)
        #pragma unroll
        for (int j = 0; j < 4; j++) {
          float p = __expf(sA[cc][j] - mA);
          lA[j] += p;
          p_lds[wave][g * 4 + j][cc * 16 + c15] = f2bf(p);
        }
      asm volatile("s_waitcnt lgkmcnt(0)" ::: "memory");
      __builtin_amdgcn_sched_barrier(0);
      s16x8 pa0 = *(const s16x8*)&p_lds[wave][c15][g * 8];
      s16x8 pa1 = *(const s16x8*)&p_lds[wave][c15][32 + g * 8];
      asm volatile("s_waitcnt lgkmcnt(0)" ::: "memory");
      __builtin_amdgcn_sched_barrier(0);
      #pragma unroll
      for (int cf = 0; cf < 4; cf++) {
        int cv = cf * 16 + c15;
        const u16* vr = &Vs[buf][cv * 64];
        oA[cf] = mfma16(pa0, *(const s16x8*)(vr + ((g ^ (cv & 7)) << 3)), oA[cf]);
        oA[cf] = mfma16(pa1, *(const s16x8*)(vr + (((4 + g) ^ (cv & 7)) << 3)), oA[cf]);
      }
    }
    // ================= tile B: softmax + PV =================
    {
      float mx = fmaxf(fmaxf(fmaxf(sB[0][0], sB[0][1]), fmaxf(sB[0][2], sB[0][3])),
                       fmaxf(fmaxf(sB[1][0], sB[1][1]), fmaxf(sB[1][2], sB[1][3])));
      mx = fmaxf(mx, fmaxf(fmaxf(fmaxf(sB[2][0], sB[2][1]), fmaxf(sB[2][2], sB[2][3])),
                           fmaxf(fmaxf(sB[3][0], sB[3][1]), fmaxf(sB[3][2], sB[3][3]))));
      #pragma unroll
      for (int msk = 1; msk < 16; msk <<= 1) mx = fmaxf(mx, __shfl_xor(mx, msk));
      if (__any(mx > mB + 8.f)) {
        float mn = fmaxf(mB, mx);
        float corr = __expf(mB - mn);
        #pragma unroll
        for (int j = 0; j < 4; j++) lB[j] *= corr;
        #pragma unroll
        for (int cf = 0; cf < 4; cf++)
          #pragma unroll
          for (int j = 0; j < 4; j++) oB[cf][j] *= corr;
        mB = mn;
      }
      #pragma unroll
      for (int cc = 0; cc < 4; cc++)
        #pragma unroll
        for (int j = 0; j < 4; j++) {
          float p = __expf(sB[cc][j] - mB);
          lB[j] += p;
          p_lds[wave][g * 4 + j][cc * 16 + c15] = f2bf(p);
        }
      asm volatile("s_waitcnt lgkmcnt(0)" ::: "memory");
      __builtin_amdgcn_sched_barrier(0);
      s16x8 pa0 = *(const s16x8*)&p_lds[wave][c15][g * 8];
      s16x8 pa1 = *(const s16x8*)&p_lds[wave][c15][32 + g * 8];
      asm volatile("s_waitcnt lgkmcnt(0)" ::: "memory");
      __builtin_amdgcn_sched_barrier(0);
      #pragma unroll
      for (int cf = 0; cf < 4; cf++) {
        int cv = cf * 16 + c15;
        const u16* vr = &Vs[buf][cv * 64];
        oB[cf] = mfma16(pa0, *(const s16x8*)(vr + ((g ^ (cv & 7)) << 3)), oB[cf]);
        oB[cf] = mfma16(pa1, *(const s16x8*)(vr + (((4 + g) ^ (cv & 7)) << 3)), oB[cf]);
      }
    }
    __syncthreads();  // next chunk staged; all waves done with buf
  }
  // epilogue: reduce denominators across 16 key-lanes, normalize, store both tiles
  #pragma unroll
  for (int j = 0; j < 4; j++) {
    #pragma unroll
    for (int msk = 1; msk < 16; msk <<= 1) {
      lA[j] += __shfl_xor(lA[j], msk);
      lB[j] += __shfl_xor(lB[j], msk);
    }
    lA[j] = 1.0f / lA[j];
    lB[j] = 1.0f / lB[j];
  }
  #pragma unroll
  for (int j = 0; j < 4; j++) {
    int tA = tok_of(wi, n0 + g * 4 + j);
    int tB = tok_of(wi, n0 + 16 + g * 4 + j);
    u16* orA = out + (size_t)tA * NDIM + hh * 64;
    u16* orB = out + (size_t)tB * NDIM + hh * 64;
    #pragma unroll
    for (int cf = 0; cf < 4; cf++) {
      orA[cf * 16 + c15] = f2bf(oA[cf][j] * lA[j]);
      orB[cf * 16 + c15] = f2bf(oB[cf][j] * lB[j]);
    }
  }
}

extern "C" void kernel_launch(void* const* d_in, const int* in_sizes, int n_in,
                              void* d_out, int out_size, void* d_ws, size_t ws_size,
                              hipStream_t stream) {
  const float* x     = (const float*)d_in[0];
  const float* ln1_g = (const float*)d_in[1];
  const float* ln1_b = (const float*)d_in[2];
  const float* qkv_w = (const float*)d_in[3];
  const float* qkv_b = (const float*)d_in[4];
  const float* rpd   = (const float*)d_in[5];
  const float* rph   = (const float*)d_in[6];
  const float* rpw   = (const float*)d_in[7];
  const float* proj_w = (const float*)d_in[8];
  const float* proj_b = (const float*)d_in[9];
  const float* aa1_w = (const float*)d_in[10];
  const float* aa1_b = (const float*)d_in[11];
  const float* aa2_w = (const float*)d_in[12];
  const float* aa2_b = (const float*)d_in[13];
  const float* ln2_g = (const float*)d_in[14];
  const float* ln2_b = (const float*)d_in[15];
  const float* mlp1_w = (const float*)d_in[16];
  const float* mlp1_b = (const float*)d_in[17];
  const float* mlp2_w = (const float*)d_in[18];
  const float* mlp2_b = (const float*)d_in[19];
  const float* ma1_w = (const float*)d_in[20];
  const float* ma1_b = (const float*)d_in[21];
  const float* ma2_w = (const float*)d_in[22];
  const float* ma2_b = (const float*)d_in[23];
  float* out = (float*)d_out;
  char* ws = (char*)d_ws;

  // arena (explicit lifetimes; total ~157 MB)
  u16* wqkv  = (u16*)(ws + 0);          // 3538944 B
  u16* wproj = (u16*)(ws + 3538944);    // 1179648
  u16* wmlp1 = (u16*)(ws + 4718592);    // 4718592
  u16* wmlp2 = (u16*)(ws + 9437184);    // 4718592
  u16* waa1  = (u16*)(ws + 14155776);   // 294912
  u16* waa2  = (u16*)(ws + 14450688);   // 294912
  u16* wma1  = (u16*)(ws + 14745600);   // 294912
  u16* wma2  = (u16*)(ws + 15040512);   // 294912
  u16* h1    = (u16*)(ws + 15335424);   // 12.58 MB: LN1 out, then reused as attn_out
  u16* attno = h1;
  u16* qkvp  = (u16*)(ws + 27918336);   // 37.75 MB: packed Qp|Kp|Vp, then p_f32 + p_bf16
  float* p_f = (float*)(ws + 27918336);
  u16* p_bf  = (u16*)(ws + 53084160);
  u16* vtp   = (u16*)(ws + 65667072);   // 12.58 MB: V_t, then hn
  u16* hn    = vtp;
  float* h_f = (float*)(ws + 78249984); // 25.17 MB
  u16* ah    = (u16*)(ws + 103415808);  // adapter hidden, then mlp hidden (50.33 MB)
  u16* mlph  = ah;
  u16* mah   = (u16*)(ws + 153747456);  // 3.15 MB
  (void)ws_size; (void)in_sizes; (void)n_in; (void)out_size;

  u16* Qp = qkvp;
  u16* Kp = qkvp + (size_t)WHN * WHSZ;
  u16* Vp = qkvp + 2 * (size_t)WHN * WHSZ;

  WConv wc;
  wc.src[0] = qkv_w;  wc.dst[0] = wqkv;  wc.n[0] = 2304 * 768;
  wc.src[1] = proj_w; wc.dst[1] = wproj; wc.n[1] = 768 * 768;
  wc.src[2] = mlp1_w; wc.dst[2] = wmlp1; wc.n[2] = 3072 * 768;
  wc.src[3] = mlp2_w; wc.dst[3] = wmlp2; wc.n[3] = 768 * 3072;
  wc.src[4] = aa1_w;  wc.dst[4] = waa1;  wc.n[4] = 192 * 768;
  wc.src[5] = aa2_w;  wc.dst[5] = waa2;  wc.n[5] = 768 * 192;
  wc.src[6] = ma1_w;  wc.dst[6] = wma1;  wc.n[6] = 192 * 768;
  wc.src[7] = ma2_w;  wc.dst[7] = wma2;  wc.n[7] = 768 * 192;
  conv_weights<<<1024, 256, 0, stream>>>(wc);

  ln_bf16<<<TOK, 256, 0, stream>>>(x, ln1_g, ln1_b, h1);
  gemm_bf16<128, 128, 6><<<dim3(64, 18), 256, 0, stream>>>(h1, wqkv, qkv_b, TOK, 2304, 768,
                                                           qkvp, nullptr, nullptr, nullptr);
  repack_v<<<192, 256, 0, stream>>>(Vp, vtp);
  attn_win<<<768, 256, 0, stream>>>(Qp, Kp, vtp, rpd, rph, rpw, attno);
  gemm_bf16<128, 64, 1><<<dim3(64, 12), 256, 0, stream>>>(attno, wproj, proj_b, TOK, 768, 768,
                                                          p_bf, p_f, nullptr, nullptr);
  gemm_bf16<64, 64, 2><<<dim3(128, 3), 256, 0, stream>>>(p_bf, waa1, aa1_b, TOK, 192, 768,
                                                         ah, nullptr, nullptr, nullptr);
  gemm_bf16<128, 64, 3><<<dim3(64, 12), 256, 0, stream>>>(ah, waa2, aa2_b, TOK, 768, 192,
                                                          nullptr, h_f, x, p_f);
  ln_bf16<<<TOK, 256, 0, stream>>>(h_f, ln2_g, ln2_b, hn);
  gemm_bf16<128, 128, 2><<<dim3(64, 24), 256, 0, stream>>>(hn, wmlp1, mlp1_b, TOK, 3072, 768,
                                                           mlph, nullptr, nullptr, nullptr);
  gemm_bf16<128, 64, 4><<<dim3(64, 12), 256, 0, stream>>>(mlph, wmlp2, mlp2_b, TOK, 768, 3072,
                                                          nullptr, out, h_f, nullptr);
  gemm_bf16<64, 64, 2><<<dim3(128, 3), 256, 0, stream>>>(hn, wma1, ma1_b, TOK, 192, 768,
                                                         mah, nullptr, nullptr, nullptr);
  gemm_bf16<128, 64, 5><<<dim3(64, 12), 256, 0, stream>>>(mah, wma2, ma2_b, TOK, 768, 192,
                                                          nullptr, out, out, nullptr);
}